// Round 1
// baseline (679.414 us; speedup 1.0000x reference)
//
#include <hip/hip_runtime.h>

// POCACritic fused forward: B=8192, N=32, OBS=128, H=256, HEADS=4 (HD=64)
// Block = 4 batch elements (wave w <-> batch blockIdx*4+w), 256 threads, MFMA bf16.

typedef __bf16 bf16x8 __attribute__((ext_vector_type(8)));
typedef float f32x4 __attribute__((ext_vector_type(4)));

#define DEVI static __device__ __forceinline__
#define MFMA16(a, b, cc) __builtin_amdgcn_mfma_f32_16x16x32_bf16((a), (b), (cc), 0, 0, 0)

// packed-weight offsets in d_ws (ushort elements)
constexpr int OWemb_ = 0;               // 16ct x 4ks x 64 x 8  = 32768
constexpr int OWq_ = 32768;             // each 16ct x 8ks x 64 x 8 = 65536
constexpr int OWk_ = OWq_ + 65536;
constexpr int OWv_ = OWk_ + 65536;
constexpr int OWo_ = OWv_ + 65536;
constexpr int OW1_ = OWo_ + 65536;
constexpr int OW2_ = OW1_ + 65536;      // total 425984 elems = 851968 B

// LDS layout (bytes)
constexpr int WB_SZ = 16896;              // per-wave [32][264] bf16: obs(stride136) -> x -> att (stride264)
constexpr int L_SCR = 4 * WB_SZ;          // 67584 ; per-wave scratch: q[32][72] k[32][72] vT[64][32]
constexpr int SCR_SZ = 13312;
constexpr int L_BST = L_SCR + 4 * SCR_SZ; // 120832 ; B-stage 32KB
constexpr int L_POOL = L_SCR;             // overlay (attn scratch dead): pooled bf16 [16][264]
constexpr int L_Y1 = L_SCR + 8448;        // y1 bf16 [16][264]
constexpr int L_PTL = L_SCR + 16896;      // float[16]
constexpr int LDS_TOTAL = L_BST + 32768;  // 153600
static_assert(LDS_TOTAL <= 160 * 1024, "LDS overflow");

DEVI unsigned short f2b(float f) {            // f32 -> bf16 RNE
  unsigned u = __float_as_uint(f);
  u += 0x7fffu + ((u >> 16) & 1u);
  return (unsigned short)(u >> 16);
}
DEVI float b2f(unsigned short s) { return __uint_as_float(((unsigned)s) << 16); }
DEVI float silu_f(float x) { return x / (1.0f + __expf(-x)); }
DEVI f32x4 splat4(float x) { f32x4 v = {x, x, x, x}; return v; }

DEVI void stageW(char* bst, const unsigned short* src, int n16, int tid) {
  const uint4* s = (const uint4*)src;
  uint4* d = (uint4*)bst;
  for (int i = tid; i < n16; i += 256) d[i] = s[i];
}

// 64-col GEMM chunk: rows 0..31 (2 row-tiles), 4 col-tiles, K = KS*32. acc preinitialized.
template <int KS>
DEVI void gemm64(const char* abase, int astride, const char* bst, int lane, int g, int c,
                 f32x4 (&acc)[2][4]) {
  #pragma unroll
  for (int ks = 0; ks < KS; ++ks) {
    bf16x8 a0 = *(const bf16x8*)(abase + c * astride + ks * 64 + g * 16);
    bf16x8 a1 = *(const bf16x8*)(abase + (c + 16) * astride + ks * 64 + g * 16);
    #pragma unroll
    for (int ct = 0; ct < 4; ++ct) {
      bf16x8 bfr = *(const bf16x8*)(bst + ((ct * KS + ks) * 64 + lane) * 16);
      acc[0][ct] = MFMA16(a0, bfr, acc[0][ct]);
      acc[1][ct] = MFMA16(a1, bfr, acc[1][ct]);
    }
  }
}

// ---- weight pre-pack: f32 (K x 256) -> bf16 B-fragment layout [ct][ks][lane][8] ----
__global__ void pack_weights(const float* __restrict__ Wemb, const float* __restrict__ Wq,
                             const float* __restrict__ Wk, const float* __restrict__ Wv,
                             const float* __restrict__ Wo, const float* __restrict__ W1,
                             const float* __restrict__ W2, unsigned short* __restrict__ ws) {
  int t = blockIdx.x * 256 + threadIdx.x;
  if (t >= 53248) return;
  const float* src;
  int dst, KS, loc;
  if (t < 4096) {
    src = Wemb; dst = OWemb_ + t * 8; KS = 4; loc = t;
  } else {
    int u = t - 4096;
    int m = u >> 13;
    loc = u & 8191; KS = 8;
    dst = OWq_ + m * 65536 + loc * 8;
    src = (m == 0) ? Wq : (m == 1) ? Wk : (m == 2) ? Wv : (m == 3) ? Wo : (m == 4) ? W1 : W2;
  }
  int l = loc & 63;
  int ks = (loc >> 6) % KS;
  int ct = loc / (64 * KS);
  int n = ct * 16 + (l & 15);
  int k0 = ks * 32 + (l >> 4) * 8;
  unsigned short v[8];
  #pragma unroll
  for (int j = 0; j < 8; ++j) v[j] = f2b(src[(k0 + j) * 256 + n]);
  uint4 pk;
  pk.x = v[0] | ((unsigned)v[1] << 16);
  pk.y = v[2] | ((unsigned)v[3] << 16);
  pk.z = v[4] | ((unsigned)v[5] << 16);
  pk.w = v[6] | ((unsigned)v[7] << 16);
  *(uint4*)(ws + dst) = pk;
}

__global__ __launch_bounds__(256, 1)
void poca_fused(const float* __restrict__ obs, const unsigned short* __restrict__ pw,
                const float* __restrict__ b_emb, const float* __restrict__ bq,
                const float* __restrict__ bk, const float* __restrict__ bv,
                const float* __restrict__ bo, const float* __restrict__ b1,
                const float* __restrict__ b2, const float* __restrict__ Wval,
                const float* __restrict__ bval, float* __restrict__ out) {
  __shared__ char lds[LDS_TOTAL];
  const int tid = threadIdx.x;
  const int w = tid >> 6;        // wave = batch within block
  const int lane = tid & 63;
  const int g = lane >> 4;       // 4-lane-group (D rows 4g..4g+3)
  const int c = lane & 15;       // D column / A row lane
  char* wb = lds + w * WB_SZ;
  char* qb = lds + L_SCR + w * SCR_SZ;
  char* kb = qb + 4608;
  char* vb = qb + 9216;
  char* bst = lds + L_BST;

  // ---- stage obs -> bf16 LDS [32][136] (stride 272B) ----
  {
    const float4* op = (const float4*)(obs + (size_t)(blockIdx.x * 4 + w) * (32 * 128));
    #pragma unroll
    for (int it = 0; it < 16; ++it) {
      int e4 = it * 64 + lane;
      float4 v = op[e4];
      int row = e4 >> 5, col = (e4 & 31) * 4;
      unsigned lo = f2b(v.x) | ((unsigned)f2b(v.y) << 16);
      unsigned hi = f2b(v.z) | ((unsigned)f2b(v.w) << 16);
      *(uint2*)(wb + row * 272 + col * 2) = make_uint2(lo, hi);
    }
  }

  // ===== GEMM1: ent = silu(obs @ Wemb + b_emb) =====
  f32x4 eacc[2][16];
  #pragma unroll
  for (int ch = 0; ch < 4; ++ch) {
    __syncthreads();
    stageW(bst, pw + OWemb_ + ch * 8192, 1024, tid);
    __syncthreads();
    f32x4 a2[2][4];
    #pragma unroll
    for (int ct = 0; ct < 4; ++ct) {
      f32x4 v = splat4(b_emb[(ch * 4 + ct) * 16 + c]);
      a2[0][ct] = v; a2[1][ct] = v;
    }
    gemm64<4>(wb, 272, bst, lane, g, c, a2);
    #pragma unroll
    for (int rt = 0; rt < 2; ++rt)
      #pragma unroll
      for (int ct = 0; ct < 4; ++ct) eacc[rt][ch * 4 + ct] = a2[rt][ct];
  }
  // silu
  #pragma unroll
  for (int rt = 0; rt < 2; ++rt)
    #pragma unroll
    for (int q2 = 0; q2 < 16; ++q2)
      #pragma unroll
      for (int r = 0; r < 4; ++r) eacc[rt][q2][r] = silu_f(eacc[rt][q2][r]);

  // LN1 -> x (bf16 to LDS stride 264; residual kept packed in regs)
  unsigned respk[2][16][2];
  {
    float mean_[2][4], rstd_[2][4];
    #pragma unroll
    for (int rt = 0; rt < 2; ++rt)
      #pragma unroll
      for (int r = 0; r < 4; ++r) {
        float s1 = 0.f, s2 = 0.f;
        #pragma unroll
        for (int q2 = 0; q2 < 16; ++q2) { float e = eacc[rt][q2][r]; s1 += e; s2 += e * e; }
        #pragma unroll
        for (int m = 1; m < 16; m <<= 1) { s1 += __shfl_xor(s1, m); s2 += __shfl_xor(s2, m); }
        float mu = s1 * (1.f / 256.f);
        float va = s2 * (1.f / 256.f) - mu * mu;
        mean_[rt][r] = mu;
        rstd_[rt][r] = rsqrtf(va + 1e-5f);
      }
    #pragma unroll
    for (int rt = 0; rt < 2; ++rt)
      #pragma unroll
      for (int q2 = 0; q2 < 16; ++q2)
        #pragma unroll
        for (int p = 0; p < 2; ++p) {
          unsigned short u0 = f2b((eacc[rt][q2][2 * p] - mean_[rt][2 * p]) * rstd_[rt][2 * p]);
          unsigned short u1 = f2b((eacc[rt][q2][2 * p + 1] - mean_[rt][2 * p + 1]) * rstd_[rt][2 * p + 1]);
          respk[rt][q2][p] = u0 | ((unsigned)u1 << 16);
          int colb = (q2 * 16 + c) * 2;
          *(unsigned short*)(wb + (rt * 16 + g * 4 + 2 * p) * 528 + colb) = u0;
          *(unsigned short*)(wb + (rt * 16 + g * 4 + 2 * p + 1) * 528 + colb) = u1;
        }
  }

  // ===== QKV + attention, per head =====
  unsigned attpk[4][2][4][2];
  #pragma unroll
  for (int h = 0; h < 4; ++h) {
    f32x4 qa[2][4], ka[2][4], va[2][4];
    // q
    __syncthreads();
    stageW(bst, pw + OWq_ + h * 16384, 2048, tid);
    __syncthreads();
    #pragma unroll
    for (int ct = 0; ct < 4; ++ct) { f32x4 v = splat4(bq[h * 64 + ct * 16 + c]); qa[0][ct] = v; qa[1][ct] = v; }
    gemm64<8>(wb, 528, bst, lane, g, c, qa);
    #pragma unroll
    for (int rt = 0; rt < 2; ++rt)
      #pragma unroll
      for (int ct = 0; ct < 4; ++ct)
        #pragma unroll
        for (int r = 0; r < 4; ++r)
          *(unsigned short*)(qb + (rt * 16 + g * 4 + r) * 144 + (ct * 16 + c) * 2) = f2b(qa[rt][ct][r]);
    // k
    __syncthreads();
    stageW(bst, pw + OWk_ + h * 16384, 2048, tid);
    __syncthreads();
    #pragma unroll
    for (int ct = 0; ct < 4; ++ct) { f32x4 v = splat4(bk[h * 64 + ct * 16 + c]); ka[0][ct] = v; ka[1][ct] = v; }
    gemm64<8>(wb, 528, bst, lane, g, c, ka);
    #pragma unroll
    for (int rt = 0; rt < 2; ++rt)
      #pragma unroll
      for (int ct = 0; ct < 4; ++ct)
        #pragma unroll
        for (int r = 0; r < 4; ++r)
          *(unsigned short*)(kb + (rt * 16 + g * 4 + r) * 144 + (ct * 16 + c) * 2) = f2b(ka[rt][ct][r]);
    // v (stored transposed: vT[d][m], stride 64B)
    __syncthreads();
    stageW(bst, pw + OWv_ + h * 16384, 2048, tid);
    __syncthreads();
    #pragma unroll
    for (int ct = 0; ct < 4; ++ct) { f32x4 v = splat4(bv[h * 64 + ct * 16 + c]); va[0][ct] = v; va[1][ct] = v; }
    gemm64<8>(wb, 528, bst, lane, g, c, va);
    #pragma unroll
    for (int rt = 0; rt < 2; ++rt)
      #pragma unroll
      for (int ct = 0; ct < 4; ++ct)
        #pragma unroll
        for (int r = 0; r < 4; ++r)
          *(unsigned short*)(vb + (ct * 16 + c) * 64 + (rt * 16 + g * 4 + r) * 2) = f2b(va[rt][ct][r]);
    __threadfence_block();

    // S = q @ k^T * 0.125  (B-frag of k^T == A-style read of k)
    f32x4 sa[2][2];
    sa[0][0] = splat4(0.f); sa[0][1] = splat4(0.f); sa[1][0] = splat4(0.f); sa[1][1] = splat4(0.f);
    #pragma unroll
    for (int ks = 0; ks < 2; ++ks) {
      bf16x8 a0 = *(const bf16x8*)(qb + c * 144 + ks * 64 + g * 16);
      bf16x8 a1 = *(const bf16x8*)(qb + (c + 16) * 144 + ks * 64 + g * 16);
      #pragma unroll
      for (int ct = 0; ct < 2; ++ct) {
        bf16x8 bfr = *(const bf16x8*)(kb + (ct * 16 + c) * 144 + ks * 64 + g * 16);
        sa[0][ct] = MFMA16(a0, bfr, sa[0][ct]);
        sa[1][ct] = MFMA16(a1, bfr, sa[1][ct]);
      }
    }
    // softmax over cols; write unnormalized P (bf16) into qb (stride 80B)
    float rinv[2][4];
    #pragma unroll
    for (int rt = 0; rt < 2; ++rt)
      #pragma unroll
      for (int r = 0; r < 4; ++r) {
        float s0 = sa[rt][0][r] * 0.125f, s1 = sa[rt][1][r] * 0.125f;
        float mx = fmaxf(s0, s1);
        #pragma unroll
        for (int m = 1; m < 16; m <<= 1) mx = fmaxf(mx, __shfl_xor(mx, m));
        float p0 = __expf(s0 - mx), p1 = __expf(s1 - mx);
        float sm = p0 + p1;
        #pragma unroll
        for (int m = 1; m < 16; m <<= 1) sm += __shfl_xor(sm, m);
        rinv[rt][r] = 1.0f / sm;
        int row = rt * 16 + g * 4 + r;
        *(unsigned short*)(qb + row * 80 + c * 2) = f2b(p0);
        *(unsigned short*)(qb + row * 80 + (16 + c) * 2) = f2b(p1);
      }
    __threadfence_block();
    // O = P @ v, then row-scale by 1/sum; pack bf16
    f32x4 oa[2][4];
    #pragma unroll
    for (int ct = 0; ct < 4; ++ct) { oa[0][ct] = splat4(0.f); oa[1][ct] = splat4(0.f); }
    {
      bf16x8 p0f = *(const bf16x8*)(qb + c * 80 + g * 16);
      bf16x8 p1f = *(const bf16x8*)(qb + (c + 16) * 80 + g * 16);
      #pragma unroll
      for (int ct = 0; ct < 4; ++ct) {
        bf16x8 bfr = *(const bf16x8*)(vb + (ct * 16 + c) * 64 + g * 16);
        oa[0][ct] = MFMA16(p0f, bfr, oa[0][ct]);
        oa[1][ct] = MFMA16(p1f, bfr, oa[1][ct]);
      }
    }
    #pragma unroll
    for (int rt = 0; rt < 2; ++rt)
      #pragma unroll
      for (int ct = 0; ct < 4; ++ct)
        #pragma unroll
        for (int p = 0; p < 2; ++p)
          attpk[h][rt][ct][p] = (unsigned)f2b(oa[rt][ct][2 * p] * rinv[rt][2 * p]) |
                                ((unsigned)f2b(oa[rt][ct][2 * p + 1] * rinv[rt][2 * p + 1]) << 16);
  }

  // write attention output into wb (x fully consumed; same region, stride 264)
  #pragma unroll
  for (int h = 0; h < 4; ++h)
    #pragma unroll
    for (int rt = 0; rt < 2; ++rt)
      #pragma unroll
      for (int ct = 0; ct < 4; ++ct)
        #pragma unroll
        for (int p = 0; p < 2; ++p) {
          unsigned u = attpk[h][rt][ct][p];
          int colb = (h * 64 + ct * 16 + c) * 2;
          *(unsigned short*)(wb + (rt * 16 + g * 4 + 2 * p) * 528 + colb) = (unsigned short)u;
          *(unsigned short*)(wb + (rt * 16 + g * 4 + 2 * p + 1) * 528 + colb) = (unsigned short)(u >> 16);
        }

  // ===== O-GEMM: y = att @ Wo + bo + x  (bias+residual preloaded as C-in) =====
  f32x4 yacc[2][16];
  #pragma unroll
  for (int ch = 0; ch < 4; ++ch) {
    __syncthreads();
    stageW(bst, pw + OWo_ + ch * 16384, 2048, tid);
    __syncthreads();
    f32x4 a2[2][4];
    #pragma unroll
    for (int ct = 0; ct < 4; ++ct) {
      float bb = bo[(ch * 4 + ct) * 16 + c];
      #pragma unroll
      for (int rt = 0; rt < 2; ++rt) {
        unsigned r0 = respk[rt][ch * 4 + ct][0], r1 = respk[rt][ch * 4 + ct][1];
        f32x4 v = {bb + b2f((unsigned short)r0), bb + b2f((unsigned short)(r0 >> 16)),
                   bb + b2f((unsigned short)r1), bb + b2f((unsigned short)(r1 >> 16))};
        a2[rt][ct] = v;
      }
    }
    gemm64<8>(wb, 528, bst, lane, g, c, a2);
    #pragma unroll
    for (int rt = 0; rt < 2; ++rt)
      #pragma unroll
      for (int ct = 0; ct < 4; ++ct) yacc[rt][ch * 4 + ct] = a2[rt][ct];
  }

  // LN2 + pool over 32 agents
  float pool[16];
  #pragma unroll
  for (int q2 = 0; q2 < 16; ++q2) pool[q2] = 0.f;
  #pragma unroll
  for (int rt = 0; rt < 2; ++rt)
    #pragma unroll
    for (int r = 0; r < 4; ++r) {
      float s1 = 0.f, s2 = 0.f;
      #pragma unroll
      for (int q2 = 0; q2 < 16; ++q2) { float e = yacc[rt][q2][r]; s1 += e; s2 += e * e; }
      #pragma unroll
      for (int m = 1; m < 16; m <<= 1) { s1 += __shfl_xor(s1, m); s2 += __shfl_xor(s2, m); }
      float mu = s1 * (1.f / 256.f);
      float va = s2 * (1.f / 256.f) - mu * mu;
      float rstd = rsqrtf(va + 1e-5f);
      #pragma unroll
      for (int q2 = 0; q2 < 16; ++q2) pool[q2] += (yacc[rt][q2][r] - mu) * rstd;
    }
  #pragma unroll
  for (int q2 = 0; q2 < 16; ++q2) {
    pool[q2] += __shfl_xor(pool[q2], 16);
    pool[q2] += __shfl_xor(pool[q2], 32);
  }
  if (g == 0) {
    #pragma unroll
    for (int q2 = 0; q2 < 16; ++q2)
      *(unsigned short*)(lds + L_POOL + w * 528 + (q2 * 16 + c) * 2) = f2b(pool[q2] * (1.f / 32.f));
  }
  // zero pad rows 4..15 of pooled and y1 buffers
  for (int i = tid; i < 3168; i += 256) {
    int r = 4 + i / 264, cc = i % 264;
    *(unsigned short*)(lds + L_POOL + r * 528 + cc * 2) = 0;
    *(unsigned short*)(lds + L_Y1 + r * 528 + cc * 2) = 0;
  }
  __syncthreads();

  // ===== tail MLP (M=16 MFMA, rows 0..3 valid; wave w owns cols 64w..64w+63) =====
  f32x4 t1[4];
  #pragma unroll
  for (int ct = 0; ct < 4; ++ct) t1[ct] = splat4(b1[w * 64 + ct * 16 + c]);
  #pragma unroll
  for (int ks = 0; ks < 8; ++ks) {
    bf16x8 a = *(const bf16x8*)(lds + L_POOL + c * 528 + ks * 64 + g * 16);
    #pragma unroll
    for (int ct = 0; ct < 4; ++ct) {
      bf16x8 bfr = *(const bf16x8*)(pw + OW1_ + (((w * 4 + ct) * 8 + ks) * 64 + lane) * 8);
      t1[ct] = MFMA16(a, bfr, t1[ct]);
    }
  }
  if (g == 0) {
    #pragma unroll
    for (int ct = 0; ct < 4; ++ct)
      #pragma unroll
      for (int r = 0; r < 4; ++r)
        *(unsigned short*)(lds + L_Y1 + r * 528 + (w * 64 + ct * 16 + c) * 2) = f2b(silu_f(t1[ct][r]));
  }
  __syncthreads();
  f32x4 t2[4];
  #pragma unroll
  for (int ct = 0; ct < 4; ++ct) t2[ct] = splat4(b2[w * 64 + ct * 16 + c]);
  #pragma unroll
  for (int ks = 0; ks < 8; ++ks) {
    bf16x8 a = *(const bf16x8*)(lds + L_Y1 + c * 528 + ks * 64 + g * 16);
    #pragma unroll
    for (int ct = 0; ct < 4; ++ct) {
      bf16x8 bfr = *(const bf16x8*)(pw + OW2_ + (((w * 4 + ct) * 8 + ks) * 64 + lane) * 8);
      t2[ct] = MFMA16(a, bfr, t2[ct]);
    }
  }
  // final: out[b] = sum_o silu(y2[b][o]) * Wval[o] + Wval[256] + bval
  if (g == 0) {
    float part[4] = {0.f, 0.f, 0.f, 0.f};
    #pragma unroll
    for (int ct = 0; ct < 4; ++ct) {
      float wv = Wval[w * 64 + ct * 16 + c];
      #pragma unroll
      for (int r = 0; r < 4; ++r) part[r] += silu_f(t2[ct][r]) * wv;
    }
    #pragma unroll
    for (int m = 1; m < 16; m <<= 1) {
      #pragma unroll
      for (int r = 0; r < 4; ++r) part[r] += __shfl_xor(part[r], m);
    }
    if (c == 0) {
      #pragma unroll
      for (int r = 0; r < 4; ++r) *(float*)(lds + L_PTL + (w * 4 + r) * 4) = part[r];
    }
  }
  __syncthreads();
  if (tid < 4) {
    float s = Wval[256] + bval[0];
    #pragma unroll
    for (int ww = 0; ww < 4; ++ww) s += *(const float*)(lds + L_PTL + (ww * 4 + tid) * 4);
    out[blockIdx.x * 4 + tid] = s;
  }
}

extern "C" void kernel_launch(void* const* d_in, const int* in_sizes, int n_in,
                              void* d_out, int out_size, void* d_ws, size_t ws_size,
                              hipStream_t stream) {
  (void)in_sizes; (void)n_in; (void)out_size; (void)ws_size;
  const float* obs  = (const float*)d_in[0];
  const float* Wemb = (const float*)d_in[1];
  const float* bemb = (const float*)d_in[2];
  const float* Wq   = (const float*)d_in[3];
  const float* bq   = (const float*)d_in[4];
  const float* Wk   = (const float*)d_in[5];
  const float* bk   = (const float*)d_in[6];
  const float* Wv   = (const float*)d_in[7];
  const float* bv   = (const float*)d_in[8];
  const float* Wo   = (const float*)d_in[9];
  const float* bo   = (const float*)d_in[10];
  const float* W1   = (const float*)d_in[11];
  const float* b1   = (const float*)d_in[12];
  const float* W2   = (const float*)d_in[13];
  const float* b2   = (const float*)d_in[14];
  const float* Wval = (const float*)d_in[15];
  const float* bval = (const float*)d_in[16];
  unsigned short* ws = (unsigned short*)d_ws;
  float* out = (float*)d_out;

  pack_weights<<<208, 256, 0, stream>>>(Wemb, Wq, Wk, Wv, Wo, W1, W2, ws);
  poca_fused<<<2048, 256, 0, stream>>>(obs, ws, bemb, bq, bk, bv, bo, b1, b2, Wval, bval, out);
}

// Round 2
// 410.594 us; speedup vs baseline: 1.6547x; 1.6547x over previous
//
#include <hip/hip_runtime.h>

// POCACritic fused forward: B=8192, N=32, OBS=128, H=256, HEADS=4 (HD=64)
// R2: 512 threads (8 waves, 2 waves/batch), async global_load_lds weight staging,
// depth-2 pipelined 16KB chunks with counted vmcnt + raw s_barrier.

typedef __bf16 bf16x8 __attribute__((ext_vector_type(8)));
typedef float f32x4 __attribute__((ext_vector_type(4)));
typedef unsigned short ushort_t;

#define DEVI static __device__ __forceinline__
#define MFMA16(a, b, cc) __builtin_amdgcn_mfma_f32_16x16x32_bf16((a), (b), (cc), 0, 0, 0)

#define WAITV2 asm volatile("s_waitcnt vmcnt(2)" ::: "memory")
#define WAITV0 asm volatile("s_waitcnt vmcnt(0)" ::: "memory")
#define WAITLG asm volatile("s_waitcnt lgkmcnt(0)" ::: "memory")
#define BAR() __builtin_amdgcn_s_barrier()

// packed-weight offsets in d_ws (ushort elements)
constexpr int OWemb_ = 0;               // 4 chunks x 8192 elems (chunk: [ks4][ctl4][lane][8])
constexpr int OWq_   = 32768;           // 8 chunks x 8192 ([ks8][ctl2][lane][8])
constexpr int OWk_   = OWq_ + 65536;
constexpr int OWv_   = OWk_ + 65536;
constexpr int OWo_   = OWv_ + 65536;
constexpr int OW1_   = OWo_ + 65536;    // old layout [ct16][ks8][lane][8]
constexpr int OW2_   = OW1_ + 65536;    // total 425984 elems = 851968 B

// LDS layout (bytes)
constexpr int WB_SZ  = 16896;             // per batch: 2 halves x (16 rows x 528B). obs overlaid @272B stride.
constexpr int L_SCR  = 4 * WB_SZ;         // 67584
constexpr int SCR_SZ = 15360;             // per batch: q[32][144B] k[32][144B] vT[64][64B] P[32][64B]
constexpr int L_BST  = L_SCR + 4 * SCR_SZ;   // 129024 ; 2 x 16KB staging slots
constexpr int LDS_TOTAL = L_BST + 32768;     // 161792 <= 163840
static_assert(LDS_TOTAL <= 160 * 1024, "LDS overflow");
// tail overlays (attention scratch dead by then)
constexpr int L_PP   = L_SCR;             // f32 partial pools [8 waves][256] = 8192B
constexpr int L_POOL = L_SCR + 8192;      // bf16 [16][264] stride 528 = 8448
constexpr int L_Y1   = L_POOL + 8448;     // bf16 [16][264] = 8448
constexpr int L_PTL  = L_Y1 + 8448;       // float[8][4]

DEVI ushort_t f2b(float f) {            // f32 -> bf16 RNE
  unsigned u = __float_as_uint(f);
  u += 0x7fffu + ((u >> 16) & 1u);
  return (ushort_t)(u >> 16);
}
DEVI float b2f(ushort_t s) { return __uint_as_float(((unsigned)s) << 16); }
DEVI float silu_f(float x) { return x / (1.0f + __expf(-x)); }
DEVI f32x4 splat4(float x) { f32x4 v = {x, x, x, x}; return v; }

typedef const __attribute__((address_space(1))) unsigned int* gas_ptr;
typedef __attribute__((address_space(3))) unsigned int* las_ptr;
DEVI void gload16(const void* g, void* l) {
  __builtin_amdgcn_global_load_lds((gas_ptr)g, (las_ptr)l, 16, 0, 0);
}

// chunk source schedule: p0..3 emb, then per head h: q,q,k,k,v,v ; p28..35 Wo
constexpr int CSRC(int p) {
  return (p < 4) ? (OWemb_ + p * 8192)
       : (p < 28) ? ((((p - 4) % 6) < 2) ? (OWq_ + (2 * ((p - 4) / 6) + (p - 4) % 6) * 8192)
                   : (((p - 4) % 6) < 4) ? (OWk_ + (2 * ((p - 4) / 6) + (p - 4) % 6 - 2) * 8192)
                                         : (OWv_ + (2 * ((p - 4) / 6) + (p - 4) % 6 - 4) * 8192))
       : (OWo_ + (p - 28) * 8192);
}

DEVI void issue_chunk(const ushort_t* pw, int srcOff, char* bst, int slot, int wv, int lane) {
  char* dst = bst + slot * 16384 + wv * 2048;
  const ushort_t* s = pw + srcOff + wv * 1024 + (size_t)lane * 8;
  gload16(s, dst);
  gload16(s + 512, dst + 1024);
}
#define PH_ISSUE(p) issue_chunk(pw, CSRC(p), bst, (p) & 1, wv, lane)

// 32-col chunk GEMM: KS=8 (K=256), NCTL=2
DEVI void gchunk8(const char* abase, int astride, const char* bstc, int lane, int g, int c,
                  f32x4 (&acc)[2]) {
  #pragma unroll
  for (int ks = 0; ks < 8; ++ks) {
    bf16x8 a = *(const bf16x8*)(abase + c * astride + ks * 64 + g * 16);
    #pragma unroll
    for (int ctl = 0; ctl < 2; ++ctl) {
      bf16x8 b = *(const bf16x8*)(bstc + ((ks * 2 + ctl) * 64 + lane) * 16);
      acc[ctl] = MFMA16(a, b, acc[ctl]);
    }
  }
}
// 64-col chunk GEMM: KS=4 (K=128), NCTL=4 (emb)
DEVI void gchunk4(const char* abase, int astride, const char* bstc, int lane, int g, int c,
                  f32x4 (&acc)[4]) {
  #pragma unroll
  for (int ks = 0; ks < 4; ++ks) {
    bf16x8 a = *(const bf16x8*)(abase + c * astride + ks * 64 + g * 16);
    #pragma unroll
    for (int ctl = 0; ctl < 4; ++ctl) {
      bf16x8 b = *(const bf16x8*)(bstc + ((ks * 4 + ctl) * 64 + lane) * 16);
      acc[ctl] = MFMA16(a, b, acc[ctl]);
    }
  }
}

// ---- weight pre-pack: f32 (K x 256) -> bf16 fragment layouts ----
__global__ void pack_weights(const float* __restrict__ Wemb, const float* __restrict__ Wq,
                             const float* __restrict__ Wk, const float* __restrict__ Wv,
                             const float* __restrict__ Wo, const float* __restrict__ W1,
                             const float* __restrict__ W2, ushort_t* __restrict__ ws) {
  int t = blockIdx.x * 256 + threadIdx.x;
  if (t >= 53248) return;
  const float* src;
  int dst, n, k0;
  if (t < 4096) {                       // emb: chunked KS=4 NCTL=4
    int loc = t;
    int ch = loc >> 10, r2 = loc & 1023, ln = r2 & 63, q2 = r2 >> 6;
    int ks = q2 >> 2, ctl = q2 & 3;
    n = ch * 64 + ctl * 16 + (ln & 15);
    k0 = ks * 32 + (ln >> 4) * 8;
    src = Wemb; dst = OWemb_ + loc * 8;
  } else if (t < 36864) {               // q,k,v,o: chunked KS=8 NCTL=2
    int u = t - 4096, m = u >> 13, loc = u & 8191;
    int ch = loc >> 10, r2 = loc & 1023, ln = r2 & 63, q2 = r2 >> 6;
    int ks = q2 >> 1, ctl = q2 & 1;
    n = ch * 32 + ctl * 16 + (ln & 15);
    k0 = ks * 32 + (ln >> 4) * 8;
    src = (m == 0) ? Wq : (m == 1) ? Wk : (m == 2) ? Wv : Wo;
    dst = OWq_ + m * 65536 + loc * 8;
  } else {                              // W1,W2: old layout [ct][ks][lane][8]
    int u = t - 36864, m = u >> 13, loc = u & 8191;
    int ln = loc & 63, ks = (loc >> 6) & 7, ct = loc >> 9;
    n = ct * 16 + (ln & 15);
    k0 = ks * 32 + (ln >> 4) * 8;
    src = m ? W2 : W1; dst = OW1_ + m * 65536 + loc * 8;
  }
  ushort_t v[8];
  #pragma unroll
  for (int j = 0; j < 8; ++j) v[j] = f2b(src[(k0 + j) * 256 + n]);
  uint4 pk;
  pk.x = v[0] | ((unsigned)v[1] << 16);
  pk.y = v[2] | ((unsigned)v[3] << 16);
  pk.z = v[4] | ((unsigned)v[5] << 16);
  pk.w = v[6] | ((unsigned)v[7] << 16);
  *(uint4*)(ws + dst) = pk;
}

__global__ __launch_bounds__(512, 2)
void poca_fused(const float* __restrict__ obs, const ushort_t* __restrict__ pw,
                const float* __restrict__ b_emb, const float* __restrict__ bq,
                const float* __restrict__ bk, const float* __restrict__ bv,
                const float* __restrict__ bo, const float* __restrict__ b1,
                const float* __restrict__ b2, const float* __restrict__ Wval,
                const float* __restrict__ bval, float* __restrict__ out) {
  __shared__ __align__(128) char lds[LDS_TOTAL];
  const int tid = threadIdx.x;
  const int wv = tid >> 6, lane = tid & 63;
  const int g = lane >> 4, c = lane & 15;
  const int bi = wv >> 1, rt = wv & 1;
  char* wbw = lds + bi * WB_SZ + rt * 8448;     // wave-private 16-row half (obs -> x -> att)
  char* scr = lds + L_SCR + bi * SCR_SZ;        // per-batch attn scratch
  char* qb = scr;            // [32][144B]
  char* kb = scr + 4608;     // [32][144B]
  char* vb = scr + 9216;     // vT [64][64B]
  char* pb = scr + 13312;    // P  [32][64B]
  char* bst = lds + L_BST;

  // bias preloads needed as C-init across phases
  float bemb_r[16], bo_r[16];
  #pragma unroll
  for (int t2 = 0; t2 < 16; ++t2) { bemb_r[t2] = b_emb[t2 * 16 + c]; bo_r[t2] = bo[t2 * 16 + c]; }

  PH_ISSUE(0);

  // ---- stage obs (own 16 rows) -> bf16 LDS stride 272B ----
  {
    const float4* op = (const float4*)(obs + (((size_t)blockIdx.x * 4 + bi) * 32 + rt * 16) * 128);
    #pragma unroll
    for (int it = 0; it < 8; ++it) {
      int e4 = it * 64 + lane;
      float4 v = op[e4];
      int row = e4 >> 5, col4 = e4 & 31;
      unsigned lo = f2b(v.x) | ((unsigned)f2b(v.y) << 16);
      unsigned hi = f2b(v.z) | ((unsigned)f2b(v.w) << 16);
      *(uint2*)(wbw + row * 272 + col4 * 8) = make_uint2(lo, hi);
    }
  }

  // ===== GEMM1: ent = silu(obs @ Wemb + b_emb) ; phases 0..3 =====
  f32x4 eacc[16];
  #pragma unroll
  for (int ch = 0; ch < 4; ++ch) {
    PH_ISSUE(ch + 1);
    WAITV2; BAR();
    f32x4 a4[4];
    #pragma unroll
    for (int ctl = 0; ctl < 4; ++ctl) a4[ctl] = splat4(bemb_r[ch * 4 + ctl]);
    gchunk4(wbw, 272, bst + (ch & 1) * 16384, lane, g, c, a4);
    #pragma unroll
    for (int ctl = 0; ctl < 4; ++ctl) eacc[ch * 4 + ctl] = a4[ctl];
    WAITLG; BAR();
  }

  // ---- interlude: silu + LN1 -> x (bf16, stride 528); residual kept packed ----
  unsigned respk[16][2];
  {
    #pragma unroll
    for (int t4 = 0; t4 < 16; ++t4)
      #pragma unroll
      for (int r = 0; r < 4; ++r) eacc[t4][r] = silu_f(eacc[t4][r]);
    float mean_[4], rstd_[4];
    #pragma unroll
    for (int r = 0; r < 4; ++r) {
      float s1 = 0.f, s2 = 0.f;
      #pragma unroll
      for (int t4 = 0; t4 < 16; ++t4) { float e = eacc[t4][r]; s1 += e; s2 += e * e; }
      #pragma unroll
      for (int m = 1; m < 16; m <<= 1) { s1 += __shfl_xor(s1, m); s2 += __shfl_xor(s2, m); }
      float mu = s1 * (1.f / 256.f);
      float va = s2 * (1.f / 256.f) - mu * mu;
      mean_[r] = mu; rstd_[r] = rsqrtf(va + 1e-5f);
    }
    #pragma unroll
    for (int t4 = 0; t4 < 16; ++t4)
      #pragma unroll
      for (int p2 = 0; p2 < 2; ++p2) {
        ushort_t u0 = f2b((eacc[t4][2 * p2] - mean_[2 * p2]) * rstd_[2 * p2]);
        ushort_t u1 = f2b((eacc[t4][2 * p2 + 1] - mean_[2 * p2 + 1]) * rstd_[2 * p2 + 1]);
        respk[t4][p2] = u0 | ((unsigned)u1 << 16);
        *(ushort_t*)(wbw + (4 * g + 2 * p2) * 528 + (t4 * 16 + c) * 2) = u0;
        *(ushort_t*)(wbw + (4 * g + 2 * p2 + 1) * 528 + (t4 * 16 + c) * 2) = u1;
      }
  }

  // ===== QKV + attention per head ; phases 4..27 =====
  unsigned attpk[4][4][2];
  float rinv[4];

  #pragma unroll
  for (int h = 0; h < 4; ++h) {
    const int base = 4 + 6 * h;
    f32x4 qa[4], ka[4], va[4];

    // q chunks (phases base, base+1); PV of previous head at top of base
    #pragma unroll
    for (int cc = 0; cc < 2; ++cc) {
      PH_ISSUE(base + 1 + cc);
      WAITV2; BAR();
      if (cc == 0 && h > 0) {
        // ---- PV(h-1): O = P @ v, scale rows by 1/sum ----
        f32x4 oa[4] = {splat4(0.f), splat4(0.f), splat4(0.f), splat4(0.f)};
        bf16x8 ap = *(const bf16x8*)(pb + (rt * 16 + c) * 64 + g * 16);
        #pragma unroll
        for (int t4 = 0; t4 < 4; ++t4) {
          bf16x8 b = *(const bf16x8*)(vb + (t4 * 16 + c) * 64 + g * 16);
          oa[t4] = MFMA16(ap, b, oa[t4]);
        }
        #pragma unroll
        for (int t4 = 0; t4 < 4; ++t4)
          #pragma unroll
          for (int p2 = 0; p2 < 2; ++p2)
            attpk[h - 1][t4][p2] = (unsigned)f2b(oa[t4][2 * p2] * rinv[2 * p2]) |
                                   ((unsigned)f2b(oa[t4][2 * p2 + 1] * rinv[2 * p2 + 1]) << 16);
      }
      f32x4 a2[2];
      #pragma unroll
      for (int ctl = 0; ctl < 2; ++ctl) a2[ctl] = splat4(bq[h * 64 + cc * 32 + ctl * 16 + c]);
      gchunk8(wbw, 528, bst + ((base + cc) & 1) * 16384, lane, g, c, a2);
      qa[cc * 2] = a2[0]; qa[cc * 2 + 1] = a2[1];
      if (cc == 1) {  // q epilogue (wave-private rows)
        #pragma unroll
        for (int t4 = 0; t4 < 4; ++t4)
          #pragma unroll
          for (int r = 0; r < 4; ++r)
            *(ushort_t*)(qb + (rt * 16 + 4 * g + r) * 144 + (t4 * 16 + c) * 2) = f2b(qa[t4][r]);
      }
      WAITLG; BAR();
    }

    // k chunks (phases base+2, base+3)
    #pragma unroll
    for (int cc = 0; cc < 2; ++cc) {
      PH_ISSUE(base + 3 + cc);
      WAITV2; BAR();
      f32x4 a2[2];
      #pragma unroll
      for (int ctl = 0; ctl < 2; ++ctl) a2[ctl] = splat4(bk[h * 64 + cc * 32 + ctl * 16 + c]);
      gchunk8(wbw, 528, bst + ((base + 2 + cc) & 1) * 16384, lane, g, c, a2);
      ka[cc * 2] = a2[0]; ka[cc * 2 + 1] = a2[1];
      if (cc == 1) {  // k epilogue (cross-wave consumed: before lgkm+barrier)
        #pragma unroll
        for (int t4 = 0; t4 < 4; ++t4)
          #pragma unroll
          for (int r = 0; r < 4; ++r)
            *(ushort_t*)(kb + (rt * 16 + 4 * g + r) * 144 + (t4 * 16 + c) * 2) = f2b(ka[t4][r]);
      }
      WAITLG; BAR();
    }

    // v chunk 0 (phase base+4): S + softmax interlude first
    {
      PH_ISSUE(base + 5);
      WAITV2; BAR();
      // ---- S = q @ k^T * 0.125 (A = own q rows; B-frag of k^T = A-style read of k) ----
      f32x4 sa[2] = {splat4(0.f), splat4(0.f)};
      #pragma unroll
      for (int ks = 0; ks < 2; ++ks) {
        bf16x8 aq = *(const bf16x8*)(qb + (rt * 16 + c) * 144 + ks * 64 + g * 16);
        #pragma unroll
        for (int ct2 = 0; ct2 < 2; ++ct2) {
          bf16x8 bk_ = *(const bf16x8*)(kb + (ct2 * 16 + c) * 144 + ks * 64 + g * 16);
          sa[ct2] = MFMA16(aq, bk_, sa[ct2]);
        }
      }
      // softmax rows rt*16+4g+r ; write unnormalized P
      #pragma unroll
      for (int r = 0; r < 4; ++r) {
        float s0 = sa[0][r] * 0.125f, s1 = sa[1][r] * 0.125f;
        float mx = fmaxf(s0, s1);
        #pragma unroll
        for (int m = 1; m < 16; m <<= 1) mx = fmaxf(mx, __shfl_xor(mx, m));
        float p0 = __expf(s0 - mx), p1 = __expf(s1 - mx);
        float sm = p0 + p1;
        #pragma unroll
        for (int m = 1; m < 16; m <<= 1) sm += __shfl_xor(sm, m);
        rinv[r] = 1.0f / sm;
        int row = rt * 16 + 4 * g + r;
        *(ushort_t*)(pb + row * 64 + c * 2) = f2b(p0);
        *(ushort_t*)(pb + row * 64 + 32 + c * 2) = f2b(p1);
      }
      // v chunk 0 GEMM
      f32x4 a2[2];
      #pragma unroll
      for (int ctl = 0; ctl < 2; ++ctl) a2[ctl] = splat4(bv[h * 64 + ctl * 16 + c]);
      gchunk8(wbw, 528, bst + ((base + 4) & 1) * 16384, lane, g, c, a2);
      va[0] = a2[0]; va[1] = a2[1];
      WAITLG; BAR();
    }
    // v chunk 1 (phase base+5) + vT epilogue
    {
      PH_ISSUE(base + 6);   // next head's q0, or Wo chunk 0 for h=3
      WAITV2; BAR();
      f32x4 a2[2];
      #pragma unroll
      for (int ctl = 0; ctl < 2; ++ctl) a2[ctl] = splat4(bv[h * 64 + 32 + ctl * 16 + c]);
      gchunk8(wbw, 528, bst + ((base + 5) & 1) * 16384, lane, g, c, a2);
      va[2] = a2[0]; va[3] = a2[1];
      // vT epilogue: vT[d][m], 8B packed writes of 4 consecutive rows (cross-wave consumed)
      #pragma unroll
      for (int t4 = 0; t4 < 4; ++t4) {
        unsigned u0 = (unsigned)f2b(va[t4][0]) | ((unsigned)f2b(va[t4][1]) << 16);
        unsigned u1 = (unsigned)f2b(va[t4][2]) | ((unsigned)f2b(va[t4][3]) << 16);
        *(uint2*)(vb + (t4 * 16 + c) * 64 + (rt * 16 + 4 * g) * 2) = make_uint2(u0, u1);
      }
      WAITLG; BAR();
    }
  }

  // ===== O-GEMM: y = att @ Wo + bo + x ; phases 28..35 =====
  f32x4 yacc[16];
  #pragma unroll
  for (int ch = 0; ch < 8; ++ch) {
    if (ch < 7) { PH_ISSUE(29 + ch); WAITV2; } else { WAITV0; }
    BAR();
    if (ch == 0) {
      // PV(3)
      f32x4 oa[4] = {splat4(0.f), splat4(0.f), splat4(0.f), splat4(0.f)};
      bf16x8 ap = *(const bf16x8*)(pb + (rt * 16 + c) * 64 + g * 16);
      #pragma unroll
      for (int t4 = 0; t4 < 4; ++t4) {
        bf16x8 b = *(const bf16x8*)(vb + (t4 * 16 + c) * 64 + g * 16);
        oa[t4] = MFMA16(ap, b, oa[t4]);
      }
      #pragma unroll
      for (int t4 = 0; t4 < 4; ++t4)
        #pragma unroll
        for (int p2 = 0; p2 < 2; ++p2)
          attpk[3][t4][p2] = (unsigned)f2b(oa[t4][2 * p2] * rinv[2 * p2]) |
                             ((unsigned)f2b(oa[t4][2 * p2 + 1] * rinv[2 * p2 + 1]) << 16);
      // write att into wbw (overwrites x; residual kept in respk)
      #pragma unroll
      for (int h = 0; h < 4; ++h)
        #pragma unroll
        for (int t4 = 0; t4 < 4; ++t4)
          #pragma unroll
          for (int p2 = 0; p2 < 2; ++p2) {
            unsigned u = attpk[h][t4][p2];
            *(ushort_t*)(wbw + (4 * g + 2 * p2) * 528 + (h * 64 + t4 * 16 + c) * 2) = (ushort_t)u;
            *(ushort_t*)(wbw + (4 * g + 2 * p2 + 1) * 528 + (h * 64 + t4 * 16 + c) * 2) = (ushort_t)(u >> 16);
          }
    }
    f32x4 a2[2];
    #pragma unroll
    for (int ctl = 0; ctl < 2; ++ctl) {
      int t4 = ch * 2 + ctl;
      unsigned rp0 = respk[t4][0], rp1 = respk[t4][1];
      float bb = bo_r[t4];
      f32x4 v = {bb + b2f((ushort_t)rp0), bb + b2f((ushort_t)(rp0 >> 16)),
                 bb + b2f((ushort_t)rp1), bb + b2f((ushort_t)(rp1 >> 16))};
      a2[ctl] = v;
    }
    gchunk8(wbw, 528, bst + ((28 + ch) & 1) * 16384, lane, g, c, a2);
    yacc[ch * 2] = a2[0]; yacc[ch * 2 + 1] = a2[1];
    WAITLG; BAR();
  }

  // ---- LN2 + pool over own 16 rows; combine wave pair via LDS f32 partials ----
  {
    float pool[16];
    #pragma unroll
    for (int t4 = 0; t4 < 16; ++t4) pool[t4] = 0.f;
    #pragma unroll
    for (int r = 0; r < 4; ++r) {
      float s1 = 0.f, s2 = 0.f;
      #pragma unroll
      for (int t4 = 0; t4 < 16; ++t4) { float e = yacc[t4][r]; s1 += e; s2 += e * e; }
      #pragma unroll
      for (int m = 1; m < 16; m <<= 1) { s1 += __shfl_xor(s1, m); s2 += __shfl_xor(s2, m); }
      float mu = s1 * (1.f / 256.f);
      float va = s2 * (1.f / 256.f) - mu * mu;
      float rstd = rsqrtf(va + 1e-5f);
      #pragma unroll
      for (int t4 = 0; t4 < 16; ++t4) pool[t4] += (yacc[t4][r] - mu) * rstd;
    }
    #pragma unroll
    for (int t4 = 0; t4 < 16; ++t4) {
      pool[t4] += __shfl_xor(pool[t4], 16);
      pool[t4] += __shfl_xor(pool[t4], 32);
    }
    if (g == 0) {
      #pragma unroll
      for (int t4 = 0; t4 < 16; ++t4)
        *(float*)(lds + L_PP + wv * 1024 + (t4 * 16 + c) * 4) = pool[t4];
    }
  }
  WAITLG; BAR();
  // build pooled bf16 [16][264] (rows 0..3 = batches; rows 4..15 zero) + zero y1 pad
  {
    const float* ppf = (const float*)(lds + L_PP);
    #pragma unroll
    for (int it = 0; it < 2; ++it) {
      int idx = it * 512 + tid;
      int row = idx >> 8, col = idx & 255;
      float v = (ppf[(2 * row) * 256 + col] + ppf[(2 * row + 1) * 256 + col]) * (1.f / 32.f);
      *(ushort_t*)(lds + L_POOL + row * 528 + col * 2) = f2b(v);
    }
    #pragma unroll
    for (int it = 0; it < 6; ++it) {
      int idx = it * 512 + tid;
      int row = 4 + (idx >> 8), col = idx & 255;
      *(ushort_t*)(lds + L_POOL + row * 528 + col * 2) = 0;
      *(ushort_t*)(lds + L_Y1 + row * 528 + col * 2) = 0;
    }
  }
  WAITLG; BAR();

  // ===== tail MLP: M=16 MFMA; wave wv owns cols wv*32..wv*32+31 =====
  f32x4 t1[2];
  #pragma unroll
  for (int ctl = 0; ctl < 2; ++ctl) t1[ctl] = splat4(b1[wv * 32 + ctl * 16 + c]);
  #pragma unroll
  for (int ks = 0; ks < 8; ++ks) {
    bf16x8 a = *(const bf16x8*)(lds + L_POOL + c * 528 + ks * 64 + g * 16);
    #pragma unroll
    for (int ctl = 0; ctl < 2; ++ctl) {
      bf16x8 b = *(const bf16x8*)(pw + OW1_ + (size_t)(((wv * 2 + ctl) * 8 + ks) * 64 + lane) * 8);
      t1[ctl] = MFMA16(a, b, t1[ctl]);
    }
  }
  if (g == 0) {
    #pragma unroll
    for (int ctl = 0; ctl < 2; ++ctl)
      #pragma unroll
      for (int r = 0; r < 4; ++r)
        *(ushort_t*)(lds + L_Y1 + r * 528 + (wv * 32 + ctl * 16 + c) * 2) = f2b(silu_f(t1[ctl][r]));
  }
  WAITLG; BAR();
  f32x4 t2[2];
  #pragma unroll
  for (int ctl = 0; ctl < 2; ++ctl) t2[ctl] = splat4(b2[wv * 32 + ctl * 16 + c]);
  #pragma unroll
  for (int ks = 0; ks < 8; ++ks) {
    bf16x8 a = *(const bf16x8*)(lds + L_Y1 + c * 528 + ks * 64 + g * 16);
    #pragma unroll
    for (int ctl = 0; ctl < 2; ++ctl) {
      bf16x8 b = *(const bf16x8*)(pw + OW2_ + (size_t)(((wv * 2 + ctl) * 8 + ks) * 64 + lane) * 8);
      t2[ctl] = MFMA16(a, b, t2[ctl]);
    }
  }
  if (g == 0) {
    float part[4] = {0.f, 0.f, 0.f, 0.f};
    #pragma unroll
    for (int ctl = 0; ctl < 2; ++ctl) {
      float wvv = Wval[wv * 32 + ctl * 16 + c];
      #pragma unroll
      for (int r = 0; r < 4; ++r) part[r] += silu_f(t2[ctl][r]) * wvv;
    }
    #pragma unroll
    for (int m = 1; m < 16; m <<= 1) {
      #pragma unroll
      for (int r = 0; r < 4; ++r) part[r] += __shfl_xor(part[r], m);
    }
    if (c == 0) {
      float4 p4 = make_float4(part[0], part[1], part[2], part[3]);
      *(float4*)(lds + L_PTL + wv * 16) = p4;
    }
  }
  WAITLG; BAR();
  if (tid < 4) {
    float s = Wval[256] + bval[0];
    const float* pt = (const float*)(lds + L_PTL);
    #pragma unroll
    for (int w8 = 0; w8 < 8; ++w8) s += pt[w8 * 4 + tid];
    out[(size_t)blockIdx.x * 4 + tid] = s;
  }
}

extern "C" void kernel_launch(void* const* d_in, const int* in_sizes, int n_in,
                              void* d_out, int out_size, void* d_ws, size_t ws_size,
                              hipStream_t stream) {
  (void)in_sizes; (void)n_in; (void)out_size; (void)ws_size;
  const float* obs  = (const float*)d_in[0];
  const float* Wemb = (const float*)d_in[1];
  const float* bemb = (const float*)d_in[2];
  const float* Wq   = (const float*)d_in[3];
  const float* bq   = (const float*)d_in[4];
  const float* Wk   = (const float*)d_in[5];
  const float* bk   = (const float*)d_in[6];
  const float* Wv   = (const float*)d_in[7];
  const float* bv   = (const float*)d_in[8];
  const float* Wo   = (const float*)d_in[9];
  const float* bo   = (const float*)d_in[10];
  const float* W1   = (const float*)d_in[11];
  const float* b1   = (const float*)d_in[12];
  const float* W2   = (const float*)d_in[13];
  const float* b2   = (const float*)d_in[14];
  const float* Wval = (const float*)d_in[15];
  const float* bval = (const float*)d_in[16];
  ushort_t* ws = (ushort_t*)d_ws;
  float* out = (float*)d_out;

  pack_weights<<<208, 256, 0, stream>>>(Wemb, Wq, Wk, Wv, Wo, W1, W2, ws);
  poca_fused<<<2048, 512, 0, stream>>>(obs, ws, bemb, bq, bk, bv, bo, b1, b2, Wval, bval, out);
}

// Round 3
// 360.044 us; speedup vs baseline: 1.8870x; 1.1404x over previous
//
#include <hip/hip_runtime.h>

// POCACritic fused forward: B=8192, N=32, OBS=128, H=256, HEADS=4 (HD=64)
// R3: output-stationary restructure. Block = 4 batches (128 rows), 8 waves =
// 2(m-groups) x 4(n-groups). Weights are MFMA A-operand (regs = n axis),
// activations are B-operand read A-style from row-major LDS. Staged chunk =
// one 32-wide K-slice of a full 256-col weight matrix (16KB), depth-2 vmcnt
// pipeline as R2. Attention fully wave-local (head = ng).

typedef __bf16 bf16x8 __attribute__((ext_vector_type(8)));
typedef float f32x4 __attribute__((ext_vector_type(4)));
typedef unsigned short ushort_t;

#define DEVI static __device__ __forceinline__
#define MFMA16(a, b, cc) __builtin_amdgcn_mfma_f32_16x16x32_bf16((a), (b), (cc), 0, 0, 0)

#define WAITV2 asm volatile("s_waitcnt vmcnt(2)" ::: "memory")
#define WAITV0 asm volatile("s_waitcnt vmcnt(0)" ::: "memory")
#define WAITLG asm volatile("s_waitcnt lgkmcnt(0)" ::: "memory")
#define BAR() __builtin_amdgcn_s_barrier()

// packed-weight offsets (ushort elems). Chunk = ks-slice: [16 ct][64 lane][8]
constexpr int OWemb_ = 0;               // 4 chunks (K=128)
constexpr int OWq_   = 32768;           // 8 chunks each (K=256)
constexpr int OWk_   = OWq_ + 65536;
constexpr int OWv_   = OWk_ + 65536;
constexpr int OWo_   = OWv_ + 65536;
constexpr int OW1_   = OWo_ + 65536;    // tail layout [ct16][ks8][lane][8]
constexpr int OW2_   = OW1_ + 65536;

// LDS layout (bytes)
constexpr int L_X    = 0;                    // x/att [128][528]; obs overlay [128][272]
constexpr int L_BIAS = 67584;                // f32 [5][256] = 5120
constexpr int L_PP   = L_BIAS + 5120;        // 72704: f32 partials [128 rows][4 ng][2]
constexpr int L_ATT  = L_PP + 4096;          // 76800: per-wave attn slots
constexpr int ATT_ST = 4672;                 // q-half [32][72] @0, k-half @2304; vT [64][72] overlays
constexpr int L_BST  = L_ATT + 8 * ATT_ST;   // 114176: 2 x 16KB staging
constexpr int LDS_TOTAL = L_BST + 32768;     // 146944
static_assert(LDS_TOTAL <= 160 * 1024, "LDS overflow");
// tail overlays (attn slots dead)
constexpr int L_POOL = L_ATT;                // bf16 [16][264] stride 528
constexpr int L_Y1   = L_POOL + 8448;
constexpr int L_PTL  = L_Y1 + 8448;          // float[8][4]

DEVI ushort_t f2b(float f) {
  unsigned u = __float_as_uint(f);
  u += 0x7fffu + ((u >> 16) & 1u);
  return (ushort_t)(u >> 16);
}
DEVI float b2f(ushort_t s) { return __uint_as_float(((unsigned)s) << 16); }
DEVI float silu_f(float x) { return x / (1.0f + __expf(-x)); }
DEVI f32x4 splat4(float x) { f32x4 v = {x, x, x, x}; return v; }
DEVI uint2 pack4(f32x4 v) {
  uint2 r;
  r.x = (unsigned)f2b(v[0]) | ((unsigned)f2b(v[1]) << 16);
  r.y = (unsigned)f2b(v[2]) | ((unsigned)f2b(v[3]) << 16);
  return r;
}
DEVI f32x4 unpk(uint2 u) {
  f32x4 v = {b2f((ushort_t)u.x), b2f((ushort_t)(u.x >> 16)),
             b2f((ushort_t)u.y), b2f((ushort_t)(u.y >> 16))};
  return v;
}
DEVI bf16x8 ld_frag(const char* p) { return *(const bf16x8*)p; }
DEVI bf16x8 u4b(unsigned a, unsigned b, unsigned cc, unsigned d) {
  union { unsigned u[4]; bf16x8 v; } x;
  x.u[0] = a; x.u[1] = b; x.u[2] = cc; x.u[3] = d;
  return x.v;
}

typedef const __attribute__((address_space(1))) unsigned int* gas_ptr;
typedef __attribute__((address_space(3))) unsigned int* las_ptr;
DEVI void gload16(const void* g, void* l) {
  __builtin_amdgcn_global_load_lds((gas_ptr)g, (las_ptr)l, 16, 0, 0);
}

// phase p -> chunk source (ushort offset). 0-3 emb, 4-11 Q, 12-19 K, 20-27 V, 28-35 O
constexpr int CSRC(int p) {
  return (p < 4)  ? (OWemb_ + p * 8192)
       : (p < 12) ? (OWq_ + (p - 4) * 8192)
       : (p < 20) ? (OWk_ + (p - 12) * 8192)
       : (p < 28) ? (OWv_ + (p - 20) * 8192)
                  : (OWo_ + (p - 28) * 8192);
}

DEVI void issue_chunk(const ushort_t* pw, int srcOff, char* bst, int slot, int wv, int lane) {
  char* dst = bst + slot * 16384 + wv * 2048;
  const ushort_t* s = pw + srcOff + wv * 1024 + (size_t)lane * 8;
  gload16(s, dst);
  gload16(s + 512, dst + 1024);
}
#define PH_ISSUE(p) issue_chunk(pw, CSRC(p), bst, (p) & 1, wv, lane)

// ---- weight pre-pack ----
__global__ void pack_weights(const float* __restrict__ Wemb, const float* __restrict__ Wq,
                             const float* __restrict__ Wk, const float* __restrict__ Wv,
                             const float* __restrict__ Wo, const float* __restrict__ W1,
                             const float* __restrict__ W2, ushort_t* __restrict__ ws) {
  int t = blockIdx.x * 256 + threadIdx.x;
  if (t >= 53248) return;
  const float* src;
  int dst, n, k0;
  if (t < 4096) {                 // emb: chunk = ks-slice [4][16ct][64l][8]
    int rem = t & 1023;
    int ctg = rem >> 6, l = rem & 63;
    n = ctg * 16 + (l & 15);
    k0 = (t >> 10) * 32 + (l >> 4) * 8;
    src = Wemb; dst = OWemb_ + t * 8;
  } else if (t < 36864) {         // q,k,v,o: [8ks][16ct][64l][8]
    int u = t - 4096, m = u >> 13, loc = u & 8191;
    int rem = loc & 1023;
    int ctg = rem >> 6, l = rem & 63;
    n = ctg * 16 + (l & 15);
    k0 = (loc >> 10) * 32 + (l >> 4) * 8;
    src = (m == 0) ? Wq : (m == 1) ? Wk : (m == 2) ? Wv : Wo;
    dst = OWq_ + m * 65536 + loc * 8;
  } else {                        // W1,W2 (tail): [ct16][ks8][lane][8]
    int u = t - 36864, m = u >> 13, loc = u & 8191;
    int ln = loc & 63, ks = (loc >> 6) & 7, ct = loc >> 9;
    n = ct * 16 + (ln & 15);
    k0 = ks * 32 + (ln >> 4) * 8;
    src = m ? W2 : W1; dst = OW1_ + m * 65536 + loc * 8;
  }
  ushort_t v[8];
  #pragma unroll
  for (int j = 0; j < 8; ++j) v[j] = f2b(src[(k0 + j) * 256 + n]);
  uint4 pk;
  pk.x = v[0] | ((unsigned)v[1] << 16);
  pk.y = v[2] | ((unsigned)v[3] << 16);
  pk.z = v[4] | ((unsigned)v[5] << 16);
  pk.w = v[6] | ((unsigned)v[7] << 16);
  *(uint4*)(ws + dst) = pk;
}

__global__ __launch_bounds__(512, 2)
void poca_fused(const float* __restrict__ obs, const ushort_t* __restrict__ pw,
                const float* __restrict__ b_emb, const float* __restrict__ bq,
                const float* __restrict__ bk, const float* __restrict__ bv,
                const float* __restrict__ bo, const float* __restrict__ b1,
                const float* __restrict__ b2, const float* __restrict__ Wval,
                const float* __restrict__ bval, float* __restrict__ out) {
  __shared__ __align__(128) char lds[LDS_TOTAL];
  const int tid = threadIdx.x;
  const int wv = tid >> 6, lane = tid & 63;
  const int g = lane >> 4, c = lane & 15;
  const int mg = wv >> 2, ng = wv & 3;       // wave = (m-group, n-group/head)
  char* bst = lds + L_BST;
  char* as_ = lds + L_ATT + wv * ATT_ST;

  // ---- bias staging (f32 [5][256]: emb,q,k,v,o) ----
  for (int i = tid; i < 1280; i += 512) {
    int m = i >> 8, j = i & 255;
    const float* bp = (m == 0) ? b_emb : (m == 1) ? bq : (m == 2) ? bk : (m == 3) ? bv : bo;
    *(float*)(lds + L_BIAS + i * 4) = bp[j];
  }

  PH_ISSUE(0);

  // ---- stage obs rows wv*16..wv*16+15 -> bf16 [128][272] ----
  {
    const float4* op = (const float4*)(obs + ((size_t)blockIdx.x * 128 + wv * 16) * 128);
    #pragma unroll
    for (int it = 0; it < 8; ++it) {
      int idx = it * 64 + lane;
      float4 v = op[idx];
      int row = idx >> 5, col4 = idx & 31;
      unsigned lo = f2b(v.x) | ((unsigned)f2b(v.y) << 16);
      unsigned hi = f2b(v.z) | ((unsigned)f2b(v.w) << 16);
      *(uint2*)(lds + L_X + (wv * 16 + row) * 272 + col4 * 8) = make_uint2(lo, hi);
    }
  }
  WAITLG;  // bias + obs ds_writes drained before first barrier

  f32x4 acc[4][4];

  // ===== emb: ent = silu(obs @ Wemb + b_emb) ; phases 0..3 (K=128) =====
  #pragma unroll
  for (int p = 0; p < 4; ++p) {
    PH_ISSUE(p + 1);
    WAITV2; BAR();
    if (p == 0) {
      #pragma unroll
      for (int ct = 0; ct < 4; ++ct) {
        f32x4 bv_ = *(const f32x4*)(lds + L_BIAS + (ng * 64 + ct * 16 + g * 4) * 4);
        #pragma unroll
        for (int rt = 0; rt < 4; ++rt) acc[rt][ct] = bv_;
      }
    }
    const char* ck = bst + (p & 1) * 16384;
    bf16x8 wf[4], xf[4];
    #pragma unroll
    for (int t = 0; t < 4; ++t) wf[t] = ld_frag(ck + ((ng * 4 + t) * 64 + lane) * 16);
    #pragma unroll
    for (int t = 0; t < 4; ++t)
      xf[t] = ld_frag(lds + L_X + ((mg * 4 + t) * 16 + c) * 272 + p * 64 + g * 16);
    #pragma unroll
    for (int rt = 0; rt < 4; ++rt)
      #pragma unroll
      for (int ct = 0; ct < 4; ++ct) acc[rt][ct] = MFMA16(wf[ct], xf[rt], acc[rt][ct]);
    WAITLG; BAR();
  }

  // ---- silu + LN1 (cross-wave partial reduce) ----
  #pragma unroll
  for (int rt = 0; rt < 4; ++rt)
    #pragma unroll
    for (int ct = 0; ct < 4; ++ct)
      #pragma unroll
      for (int r = 0; r < 4; ++r) acc[rt][ct][r] = silu_f(acc[rt][ct][r]);
  #pragma unroll
  for (int rt = 0; rt < 4; ++rt) {
    float s1 = 0.f, s2 = 0.f;
    #pragma unroll
    for (int ct = 0; ct < 4; ++ct)
      #pragma unroll
      for (int r = 0; r < 4; ++r) { float e = acc[rt][ct][r]; s1 += e; s2 += e * e; }
    s1 += __shfl_xor(s1, 16); s2 += __shfl_xor(s2, 16);
    s1 += __shfl_xor(s1, 32); s2 += __shfl_xor(s2, 32);
    if (g == 0)
      *(float2*)(lds + L_PP + (mg * 64 + rt * 16 + c) * 32 + ng * 8) = make_float2(s1, s2);
  }
  WAITLG; BAR();
  uint2 respk[4][4];
  {
    float mu[4], rs[4];
    #pragma unroll
    for (int rt = 0; rt < 4; ++rt) {
      int row = mg * 64 + rt * 16 + c;
      f32x4 pA = *(const f32x4*)(lds + L_PP + row * 32);
      f32x4 pB = *(const f32x4*)(lds + L_PP + row * 32 + 16);
      float S1 = pA[0] + pA[2] + pB[0] + pB[2];
      float S2 = pA[1] + pA[3] + pB[1] + pB[3];
      float m_ = S1 * (1.f / 256.f);
      float v_ = S2 * (1.f / 256.f) - m_ * m_;
      mu[rt] = m_; rs[rt] = rsqrtf(v_ + 1e-5f);
    }
    #pragma unroll
    for (int rt = 0; rt < 4; ++rt)
      #pragma unroll
      for (int ct = 0; ct < 4; ++ct) {
        f32x4 xv;
        #pragma unroll
        for (int r = 0; r < 4; ++r) xv[r] = (acc[rt][ct][r] - mu[rt]) * rs[rt];
        uint2 xp = pack4(xv);
        respk[rt][ct] = xp;
        *(uint2*)(lds + L_X + ((mg * 4 + rt) * 16 + c) * 528 + (ng * 64 + ct * 16 + g * 4) * 2) = xp;
      }
  }
  WAITLG; BAR();

  // ===== Q (4..11), K (12..19): weights-as-A ; V (20..27): x-as-A =====
  uint2 q_pk[4][4], k_pk[4][4], v_pk[4][4];
  #pragma unroll
  for (int p = 4; p < 12; ++p) {
    PH_ISSUE(p + 1);
    WAITV2; BAR();
    if (p == 4) {
      #pragma unroll
      for (int ct = 0; ct < 4; ++ct) {
        f32x4 bv_ = *(const f32x4*)(lds + L_BIAS + 1024 + (ng * 64 + ct * 16 + g * 4) * 4);
        #pragma unroll
        for (int rt = 0; rt < 4; ++rt) acc[rt][ct] = bv_;
      }
    }
    const char* ck = bst + (p & 1) * 16384;
    bf16x8 wf[4], xf[4];
    #pragma unroll
    for (int t = 0; t < 4; ++t) wf[t] = ld_frag(ck + ((ng * 4 + t) * 64 + lane) * 16);
    #pragma unroll
    for (int t = 0; t < 4; ++t)
      xf[t] = ld_frag(lds + L_X + ((mg * 4 + t) * 16 + c) * 528 + (p - 4) * 64 + g * 16);
    #pragma unroll
    for (int rt = 0; rt < 4; ++rt)
      #pragma unroll
      for (int ct = 0; ct < 4; ++ct) acc[rt][ct] = MFMA16(wf[ct], xf[rt], acc[rt][ct]);
    WAITLG; BAR();
  }
  #pragma unroll
  for (int rt = 0; rt < 4; ++rt)
    #pragma unroll
    for (int ct = 0; ct < 4; ++ct) q_pk[rt][ct] = pack4(acc[rt][ct]);

  #pragma unroll
  for (int p = 12; p < 20; ++p) {
    PH_ISSUE(p + 1);
    WAITV2; BAR();
    if (p == 12) {
      #pragma unroll
      for (int ct = 0; ct < 4; ++ct) {
        f32x4 bv_ = *(const f32x4*)(lds + L_BIAS + 2048 + (ng * 64 + ct * 16 + g * 4) * 4);
        #pragma unroll
        for (int rt = 0; rt < 4; ++rt) acc[rt][ct] = bv_;
      }
    }
    const char* ck = bst + (p & 1) * 16384;
    bf16x8 wf[4], xf[4];
    #pragma unroll
    for (int t = 0; t < 4; ++t) wf[t] = ld_frag(ck + ((ng * 4 + t) * 64 + lane) * 16);
    #pragma unroll
    for (int t = 0; t < 4; ++t)
      xf[t] = ld_frag(lds + L_X + ((mg * 4 + t) * 16 + c) * 528 + (p - 12) * 64 + g * 16);
    #pragma unroll
    for (int rt = 0; rt < 4; ++rt)
      #pragma unroll
      for (int ct = 0; ct < 4; ++ct) acc[rt][ct] = MFMA16(wf[ct], xf[rt], acc[rt][ct]);
    WAITLG; BAR();
  }
  #pragma unroll
  for (int rt = 0; rt < 4; ++rt)
    #pragma unroll
    for (int ct = 0; ct < 4; ++ct) k_pk[rt][ct] = pack4(acc[rt][ct]);

  #pragma unroll
  for (int p = 20; p < 28; ++p) {
    PH_ISSUE(p + 1);
    WAITV2; BAR();
    if (p == 20) {
      #pragma unroll
      for (int ct = 0; ct < 4; ++ct) {
        float bb = *(const float*)(lds + L_BIAS + 3072 + (ng * 64 + ct * 16 + c) * 4);
        f32x4 s = splat4(bb);
        #pragma unroll
        for (int rt = 0; rt < 4; ++rt) acc[rt][ct] = s;
      }
    }
    const char* ck = bst + (p & 1) * 16384;
    bf16x8 wf[4], xf[4];
    #pragma unroll
    for (int t = 0; t < 4; ++t) wf[t] = ld_frag(ck + ((ng * 4 + t) * 64 + lane) * 16);
    #pragma unroll
    for (int t = 0; t < 4; ++t)
      xf[t] = ld_frag(lds + L_X + ((mg * 4 + t) * 16 + c) * 528 + (p - 20) * 64 + g * 16);
    #pragma unroll
    for (int rt = 0; rt < 4; ++rt)
      #pragma unroll
      for (int ct = 0; ct < 4; ++ct) acc[rt][ct] = MFMA16(xf[rt], wf[ct], acc[rt][ct]);  // x-as-A
    WAITLG; BAR();
  }
  #pragma unroll
  for (int rt = 0; rt < 4; ++rt)
    #pragma unroll
    for (int ct = 0; ct < 4; ++ct) v_pk[rt][ct] = pack4(acc[rt][ct]);

  // ===== attention: wave handles (batch 2mg+pb, head ng), pb=0,1 — wave-local =====
  #pragma unroll
  for (int pb = 0; pb < 2; ++pb) {
    f32x4 sacc[2][2];
    sacc[0][0] = splat4(0.f); sacc[0][1] = splat4(0.f);
    sacc[1][0] = splat4(0.f); sacc[1][1] = splat4(0.f);
    #pragma unroll
    for (int hf = 0; hf < 2; ++hf) {          // d-halves (K=64 in 2 x 32)
      #pragma unroll
      for (int rt2 = 0; rt2 < 2; ++rt2)
        #pragma unroll
        for (int ctl = 0; ctl < 2; ++ctl) {
          *(uint2*)(as_ + (rt2 * 16 + c) * 72 + (ctl * 16 + g * 4) * 2) = q_pk[pb * 2 + rt2][hf * 2 + ctl];
          *(uint2*)(as_ + 2304 + (rt2 * 16 + c) * 72 + (ctl * 16 + g * 4) * 2) = k_pk[pb * 2 + rt2][hf * 2 + ctl];
        }
      bf16x8 qf[2], kf[2];
      #pragma unroll
      for (int t = 0; t < 2; ++t) {
        qf[t] = ld_frag(as_ + (t * 16 + c) * 72 + g * 16);
        kf[t] = ld_frag(as_ + 2304 + (t * 16 + c) * 72 + g * 16);
      }
      #pragma unroll
      for (int qt = 0; qt < 2; ++qt)
        #pragma unroll
        for (int kt = 0; kt < 2; ++kt)
          sacc[qt][kt] = MFMA16(kf[kt], qf[qt], sacc[qt][kt]);   // S^T[m_k][m_q]
    }
    // softmax over m_k: in-lane (2kt x 4r) + xor16/xor32
    float rinv[2];
    uint2 p_pk[2][2];
    #pragma unroll
    for (int qt = 0; qt < 2; ++qt) {
      float sc[2][4];
      float mx = -3e38f;
      #pragma unroll
      for (int kt = 0; kt < 2; ++kt)
        #pragma unroll
        for (int r = 0; r < 4; ++r) { sc[kt][r] = sacc[qt][kt][r] * 0.125f; mx = fmaxf(mx, sc[kt][r]); }
      mx = fmaxf(mx, __shfl_xor(mx, 16));
      mx = fmaxf(mx, __shfl_xor(mx, 32));
      float sm = 0.f;
      #pragma unroll
      for (int kt = 0; kt < 2; ++kt)
        #pragma unroll
        for (int r = 0; r < 4; ++r) { float e = __expf(sc[kt][r] - mx); sc[kt][r] = e; sm += e; }
      sm += __shfl_xor(sm, 16);
      sm += __shfl_xor(sm, 32);
      rinv[qt] = 1.0f / sm;
      #pragma unroll
      for (int kt = 0; kt < 2; ++kt) {
        f32x4 pv = {sc[kt][0], sc[kt][1], sc[kt][2], sc[kt][3]};
        p_pk[qt][kt] = pack4(pv);
      }
    }
    // vT [64 d][72B] overlays q/k region (q,k dead)
    #pragma unroll
    for (int rt2 = 0; rt2 < 2; ++rt2)
      #pragma unroll
      for (int ct = 0; ct < 4; ++ct)
        *(uint2*)(as_ + (ct * 16 + c) * 72 + (rt2 * 16 + g * 4) * 2) = v_pk[pb * 2 + rt2][ct];
    // PV: O^T-free — A = vT (i=d), B = P (j=m_q, built from regs via shuffles)
    bf16x8 vf[4];
    #pragma unroll
    for (int dt = 0; dt < 4; ++dt) vf[dt] = ld_frag(as_ + (dt * 16 + c) * 72 + g * 16);
    const int l1 = (g & 1) * 32 + c, l2 = (g & 1) * 32 + 16 + c;
    const bool hi = (g >= 2);
    #pragma unroll
    for (int qt = 0; qt < 2; ++qt) {
      unsigned x0k0 = __shfl(p_pk[qt][0].x, l1), x0k1 = __shfl(p_pk[qt][1].x, l1);
      unsigned y0k0 = __shfl(p_pk[qt][0].y, l1), y0k1 = __shfl(p_pk[qt][1].y, l1);
      unsigned x1k0 = __shfl(p_pk[qt][0].x, l2), x1k1 = __shfl(p_pk[qt][1].x, l2);
      unsigned y1k0 = __shfl(p_pk[qt][0].y, l2), y1k1 = __shfl(p_pk[qt][1].y, l2);
      bf16x8 pf = u4b(hi ? x0k1 : x0k0, hi ? y0k1 : y0k0, hi ? x1k1 : x1k0, hi ? y1k1 : y1k0);
      f32x4 oacc[4];
      #pragma unroll
      for (int dt = 0; dt < 4; ++dt) {
        oacc[dt] = splat4(0.f);
        oacc[dt] = MFMA16(vf[dt], pf, oacc[dt]);
      }
      #pragma unroll
      for (int dt = 0; dt < 4; ++dt) {
        f32x4 o = oacc[dt] * rinv[qt];
        *(uint2*)(lds + L_X + (((2 * mg + pb) * 32 + qt * 16 + c) * 528) +
                  (ng * 64 + dt * 16 + g * 4) * 2) = pack4(o);
      }
    }
  }
  WAITLG; BAR();

  // ===== O-GEMM: y = att @ Wo + bo + x ; phases 28..35 =====
  #pragma unroll
  for (int p = 28; p < 36; ++p) {
    if (p < 35) { PH_ISSUE(p + 1); WAITV2; } else { WAITV0; }
    BAR();
    if (p == 28) {
      #pragma unroll
      for (int ct = 0; ct < 4; ++ct) {
        f32x4 bo_ = *(const f32x4*)(lds + L_BIAS + 4096 + (ng * 64 + ct * 16 + g * 4) * 4);
        #pragma unroll
        for (int rt = 0; rt < 4; ++rt) acc[rt][ct] = bo_ + unpk(respk[rt][ct]);
      }
    }
    const char* ck = bst + (p & 1) * 16384;
    bf16x8 wf[4], xf[4];
    #pragma unroll
    for (int t = 0; t < 4; ++t) wf[t] = ld_frag(ck + ((ng * 4 + t) * 64 + lane) * 16);
    #pragma unroll
    for (int t = 0; t < 4; ++t)
      xf[t] = ld_frag(lds + L_X + ((mg * 4 + t) * 16 + c) * 528 + (p - 28) * 64 + g * 16);
    #pragma unroll
    for (int rt = 0; rt < 4; ++rt)
      #pragma unroll
      for (int ct = 0; ct < 4; ++ct) acc[rt][ct] = MFMA16(wf[ct], xf[rt], acc[rt][ct]);
    WAITLG; BAR();
  }

  // ---- LN2 partials ----
  #pragma unroll
  for (int rt = 0; rt < 4; ++rt) {
    float s1 = 0.f, s2 = 0.f;
    #pragma unroll
    for (int ct = 0; ct < 4; ++ct)
      #pragma unroll
      for (int r = 0; r < 4; ++r) { float e = acc[rt][ct][r]; s1 += e; s2 += e * e; }
    s1 += __shfl_xor(s1, 16); s2 += __shfl_xor(s2, 16);
    s1 += __shfl_xor(s1, 32); s2 += __shfl_xor(s2, 32);
    if (g == 0)
      *(float2*)(lds + L_PP + (mg * 64 + rt * 16 + c) * 32 + ng * 8) = make_float2(s1, s2);
  }
  WAITLG; BAR();
  {
    float mu[4], rs[4];
    #pragma unroll
    for (int rt = 0; rt < 4; ++rt) {
      int row = mg * 64 + rt * 16 + c;
      f32x4 pA = *(const f32x4*)(lds + L_PP + row * 32);
      f32x4 pB = *(const f32x4*)(lds + L_PP + row * 32 + 16);
      float S1 = pA[0] + pA[2] + pB[0] + pB[2];
      float S2 = pA[1] + pA[3] + pB[1] + pB[3];
      float m_ = S1 * (1.f / 256.f);
      float v_ = S2 * (1.f / 256.f) - m_ * m_;
      mu[rt] = m_; rs[rt] = rsqrtf(v_ + 1e-5f);
    }
    // pool over 32 agents per batch; write pooled rows 0..3
    #pragma unroll
    for (int pb = 0; pb < 2; ++pb) {
      f32x4 ps[4];
      #pragma unroll
      for (int ct = 0; ct < 4; ++ct) {
        f32x4 s;
        #pragma unroll
        for (int r = 0; r < 4; ++r)
          s[r] = (acc[2 * pb][ct][r] - mu[2 * pb]) * rs[2 * pb] +
                 (acc[2 * pb + 1][ct][r] - mu[2 * pb + 1]) * rs[2 * pb + 1];
        ps[ct] = s;
      }
      #pragma unroll
      for (int st = 1; st < 16; st <<= 1)
        #pragma unroll
        for (int ct = 0; ct < 4; ++ct)
          #pragma unroll
          for (int r = 0; r < 4; ++r) ps[ct][r] += __shfl_xor(ps[ct][r], st);
      if (c == pb) {
        #pragma unroll
        for (int ct = 0; ct < 4; ++ct) {
          f32x4 pv = ps[ct] * (1.f / 32.f);
          *(uint2*)(lds + L_POOL + (2 * mg + pb) * 528 + (ng * 64 + ct * 16 + g * 4) * 2) = pack4(pv);
        }
      }
    }
  }
  // zero pooled/y1 pad rows 4..15
  for (int it = 0; it < 6; ++it) {
    int idx = it * 512 + tid;
    int row = 4 + (idx >> 8), col = idx & 255;
    *(ushort_t*)(lds + L_POOL + row * 528 + col * 2) = 0;
    *(ushort_t*)(lds + L_Y1 + row * 528 + col * 2) = 0;
  }
  WAITLG; BAR();

  // ===== tail MLP: M=16 MFMA; wave wv owns cols wv*32..wv*32+31 =====
  f32x4 t1[2];
  #pragma unroll
  for (int ctl = 0; ctl < 2; ++ctl) t1[ctl] = splat4(b1[wv * 32 + ctl * 16 + c]);
  #pragma unroll
  for (int ks = 0; ks < 8; ++ks) {
    bf16x8 a = ld_frag(lds + L_POOL + c * 528 + ks * 64 + g * 16);
    #pragma unroll
    for (int ctl = 0; ctl < 2; ++ctl) {
      bf16x8 b = *(const bf16x8*)(pw + OW1_ + (size_t)(((wv * 2 + ctl) * 8 + ks) * 64 + lane) * 8);
      t1[ctl] = MFMA16(a, b, t1[ctl]);
    }
  }
  if (g == 0) {
    #pragma unroll
    for (int ctl = 0; ctl < 2; ++ctl)
      #pragma unroll
      for (int r = 0; r < 4; ++r)
        *(ushort_t*)(lds + L_Y1 + r * 528 + (wv * 32 + ctl * 16 + c) * 2) = f2b(silu_f(t1[ctl][r]));
  }
  WAITLG; BAR();
  f32x4 t2[2];
  #pragma unroll
  for (int ctl = 0; ctl < 2; ++ctl) t2[ctl] = splat4(b2[wv * 32 + ctl * 16 + c]);
  #pragma unroll
  for (int ks = 0; ks < 8; ++ks) {
    bf16x8 a = ld_frag(lds + L_Y1 + c * 528 + ks * 64 + g * 16);
    #pragma unroll
    for (int ctl = 0; ctl < 2; ++ctl) {
      bf16x8 b = *(const bf16x8*)(pw + OW2_ + (size_t)(((wv * 2 + ctl) * 8 + ks) * 64 + lane) * 8);
      t2[ctl] = MFMA16(a, b, t2[ctl]);
    }
  }
  if (g == 0) {
    float part[4] = {0.f, 0.f, 0.f, 0.f};
    #pragma unroll
    for (int ctl = 0; ctl < 2; ++ctl) {
      float wvv = Wval[wv * 32 + ctl * 16 + c];
      #pragma unroll
      for (int r = 0; r < 4; ++r) part[r] += silu_f(t2[ctl][r]) * wvv;
    }
    #pragma unroll
    for (int m = 1; m < 16; m <<= 1) {
      #pragma unroll
      for (int r = 0; r < 4; ++r) part[r] += __shfl_xor(part[r], m);
    }
    if (c == 0) {
      float4 p4 = make_float4(part[0], part[1], part[2], part[3]);
      *(float4*)(lds + L_PTL + wv * 16) = p4;
    }
  }
  WAITLG; BAR();
  if (tid < 4) {
    float s = Wval[256] + bval[0];
    const float* pt = (const float*)(lds + L_PTL);
    #pragma unroll
    for (int w8 = 0; w8 < 8; ++w8) s += pt[w8 * 4 + tid];
    out[(size_t)blockIdx.x * 4 + tid] = s;
  }
}

extern "C" void kernel_launch(void* const* d_in, const int* in_sizes, int n_in,
                              void* d_out, int out_size, void* d_ws, size_t ws_size,
                              hipStream_t stream) {
  (void)in_sizes; (void)n_in; (void)out_size; (void)ws_size;
  const float* obs  = (const float*)d_in[0];
  const float* Wemb = (const float*)d_in[1];
  const float* bemb = (const float*)d_in[2];
  const float* Wq   = (const float*)d_in[3];
  const float* bq   = (const float*)d_in[4];
  const float* Wk   = (const float*)d_in[5];
  const float* bk   = (const float*)d_in[6];
  const float* Wv   = (const float*)d_in[7];
  const float* bv   = (const float*)d_in[8];
  const float* Wo   = (const float*)d_in[9];
  const float* bo   = (const float*)d_in[10];
  const float* W1   = (const float*)d_in[11];
  const float* b1   = (const float*)d_in[12];
  const float* W2   = (const float*)d_in[13];
  const float* b2   = (const float*)d_in[14];
  const float* Wval = (const float*)d_in[15];
  const float* bval = (const float*)d_in[16];
  ushort_t* ws = (ushort_t*)d_ws;
  float* out = (float*)d_out;

  pack_weights<<<208, 256, 0, stream>>>(Wemb, Wq, Wk, Wv, Wo, W1, W2, ws);
  poca_fused<<<2048, 512, 0, stream>>>(obs, ws, bemb, bq, bk, bv, bo, b1, b2, Wval, bval, out);
}

// Round 4
// 359.124 us; speedup vs baseline: 1.8919x; 1.0026x over previous
//
#include <hip/hip_runtime.h>

// POCACritic fused forward: B=8192, N=32, OBS=128, H=256, HEADS=4 (HD=64)
// R4: 64-row blocks (2 batches), 8 waves of 32x64 tiles, 2 blocks/CU (LDS 68.6KB).
// Frag-linear x/att LDS (conflict-free), wave-local attention (wave=(batch,head)),
// K=32 chunk pipeline D=2 with counted vmcnt, native __bf16 casts.

typedef __bf16 bf16x8 __attribute__((ext_vector_type(8)));
typedef float f32x4 __attribute__((ext_vector_type(4)));
typedef unsigned short ushort_t;

#define DEVI static __device__ __forceinline__
#define MFMA16(a, b, cc) __builtin_amdgcn_mfma_f32_16x16x32_bf16((a), (b), (cc), 0, 0, 0)

#define WAITV2 asm volatile("s_waitcnt vmcnt(2)" ::: "memory")
#define WAITV0 asm volatile("s_waitcnt vmcnt(0)" ::: "memory")
#define WAITLG asm volatile("s_waitcnt lgkmcnt(0)" ::: "memory")
#define BAR() __builtin_amdgcn_s_barrier()

// packed-weight offsets (ushort elems). Chunk = 32-K-slice: [16 ct][64 lane][8]
constexpr int OWemb_ = 0;               // 4 chunks (K=128)
constexpr int OWq_   = 32768;           // 8 chunks each (K=256)
constexpr int OWk_   = OWq_ + 65536;
constexpr int OWv_   = OWk_ + 65536;
constexpr int OWo_   = OWv_ + 65536;
constexpr int OW1_   = OWo_ + 65536;    // tail layout [ct16][ks8][lane][8]
constexpr int OW2_   = OW1_ + 65536;

// LDS layout (bytes)
constexpr int L_STAGE = 32768;            // x/att frag-linear [4t][8ks][64][16B] = 32KB at 0
constexpr int L_PP    = 65536;            // staging 2 x 16KB at 32768
constexpr int LDS_TOTAL = 65536 + 3072;   // PP f32 [64 rows][48B]
static_assert(LDS_TOTAL <= 80 * 1024, "need <=80KB for 2 blocks/CU");

DEVI float silu_f(float x) { return x / (1.0f + __expf(-x)); }
DEVI f32x4 splat4(float x) { f32x4 v = {x, x, x, x}; return v; }
DEVI uint2 pack4(f32x4 v) {               // native casts -> compiler cvt_pk (RNE)
  union { __bf16 h[4]; uint2 u; } x;
  x.h[0] = (__bf16)v[0]; x.h[1] = (__bf16)v[1];
  x.h[2] = (__bf16)v[2]; x.h[3] = (__bf16)v[3];
  return x.u;
}
DEVI f32x4 unpk(uint2 u) {
  union { uint2 u2; __bf16 h[4]; } x; x.u2 = u;
  f32x4 v = {(float)x.h[0], (float)x.h[1], (float)x.h[2], (float)x.h[3]};
  return v;
}
DEVI bf16x8 ld_frag(const char* p) { return *(const bf16x8*)p; }
DEVI bf16x8 u4b(unsigned a, unsigned b, unsigned cc, unsigned d) {
  union { unsigned u[4]; bf16x8 v; } x;
  x.u[0] = a; x.u[1] = b; x.u[2] = cc; x.u[3] = d;
  return x.v;
}
// frag-linear byte offset for 4-elem group at (row, k4) ; k4 % 4 == 0
DEVI int xaddr(int row, int k4) {
  int t = row >> 4, cc = row & 15;
  int ks = k4 >> 5, kg = (k4 >> 3) & 3, half = (k4 >> 2) & 1;
  return ((t * 8 + ks) * 64 + kg * 16 + cc) * 16 + half * 8;
}

typedef const __attribute__((address_space(1))) unsigned int* gas_ptr;
typedef __attribute__((address_space(3))) unsigned int* las_ptr;
DEVI void gload16(const void* g, void* l) {
  __builtin_amdgcn_global_load_lds((gas_ptr)g, (las_ptr)l, 16, 0, 0);
}

// phase p -> chunk source. 0-3 emb, 4-11 Q, 12-19 K, 20-27 V, 28-35 O
constexpr int CSRC(int p) {
  return (p < 4)  ? (OWemb_ + p * 8192)
       : (p < 12) ? (OWq_ + (p - 4) * 8192)
       : (p < 20) ? (OWk_ + (p - 12) * 8192)
       : (p < 28) ? (OWv_ + (p - 20) * 8192)
                  : (OWo_ + (p - 28) * 8192);
}

DEVI void issue_chunk(const ushort_t* pw, int srcOff, char* bst, int slot, int wv, int lane) {
  char* dst = bst + slot * 16384 + wv * 2048;
  const ushort_t* s = pw + srcOff + wv * 1024 + (size_t)lane * 8;
  gload16(s, dst);
  gload16(s + 512, dst + 1024);
}
#define PH_ISSUE(p) issue_chunk(pw, CSRC(p), bst, (p) & 1, wv, lane)

// ---- weight pre-pack (identical layouts to R3) ----
__global__ void pack_weights(const float* __restrict__ Wemb, const float* __restrict__ Wq,
                             const float* __restrict__ Wk, const float* __restrict__ Wv,
                             const float* __restrict__ Wo, const float* __restrict__ W1,
                             const float* __restrict__ W2, ushort_t* __restrict__ ws) {
  int t = blockIdx.x * 256 + threadIdx.x;
  if (t >= 53248) return;
  const float* src;
  int dst, n, k0;
  if (t < 4096) {                 // emb: [4ks][16ct][64l][8]
    int rem = t & 1023;
    int ctg = rem >> 6, l = rem & 63;
    n = ctg * 16 + (l & 15);
    k0 = (t >> 10) * 32 + (l >> 4) * 8;
    src = Wemb; dst = OWemb_ + t * 8;
  } else if (t < 36864) {         // q,k,v,o: [8ks][16ct][64l][8]
    int u = t - 4096, m = u >> 13, loc = u & 8191;
    int rem = loc & 1023;
    int ctg = rem >> 6, l = rem & 63;
    n = ctg * 16 + (l & 15);
    k0 = (loc >> 10) * 32 + (l >> 4) * 8;
    src = (m == 0) ? Wq : (m == 1) ? Wk : (m == 2) ? Wv : Wo;
    dst = OWq_ + m * 65536 + loc * 8;
  } else {                        // W1,W2 (tail): [ct16][ks8][lane][8]
    int u = t - 36864, m = u >> 13, loc = u & 8191;
    int ln = loc & 63, ks = (loc >> 6) & 7, ct = loc >> 9;
    n = ct * 16 + (ln & 15);
    k0 = ks * 32 + (ln >> 4) * 8;
    src = m ? W2 : W1; dst = OW1_ + m * 65536 + loc * 8;
  }
  union { __bf16 h[8]; uint4 u; } pk;
  #pragma unroll
  for (int j = 0; j < 8; ++j) pk.h[j] = (__bf16)src[(k0 + j) * 256 + n];
  *(uint4*)(ws + dst) = pk.u;
}

__global__ __launch_bounds__(512, 4)
void poca_fused(const float* __restrict__ obs, const ushort_t* __restrict__ pw,
                const float* __restrict__ b_emb, const float* __restrict__ bq,
                const float* __restrict__ bk, const float* __restrict__ bv,
                const float* __restrict__ bo, const float* __restrict__ b1,
                const float* __restrict__ b2, const float* __restrict__ Wval,
                const float* __restrict__ bval, float* __restrict__ out) {
  __shared__ __align__(128) char lds[LDS_TOTAL];
  const int tid = threadIdx.x;
  const int wv = tid >> 6, lane = tid & 63;
  const int g = lane >> 4, c = lane & 15;
  const int mg = wv >> 2, ng = wv & 3;       // wave = (batch mg, head/ncols ng)
  char* xb = lds;                            // obs (row-major 272) -> x -> att (frag-linear)
  char* bst = lds + L_STAGE;
  char* as_ = bst + wv * 4096;               // attention scratch overlays staging
  char* poolb = bst;                         // tail overlays staging
  char* y1b = bst + 8448;
  char* ptlb = bst + 16896;

  PH_ISSUE(0);

  // ---- stage obs: 64 rows x 128 f32 -> bf16 row-major stride 272 ----
  {
    const float4* op = (const float4*)(obs + (size_t)blockIdx.x * 64 * 128);
    #pragma unroll
    for (int it = 0; it < 4; ++it) {
      int idx = it * 512 + tid;              // 0..2047
      float4 v = op[idx];
      int row = idx >> 5, col4 = idx & 31;
      union { __bf16 h[4]; uint2 u; } cv;
      cv.h[0] = (__bf16)v.x; cv.h[1] = (__bf16)v.y;
      cv.h[2] = (__bf16)v.z; cv.h[3] = (__bf16)v.w;
      *(uint2*)(xb + row * 272 + col4 * 8) = cv.u;
    }
  }
  WAITLG;

  f32x4 acc[2][4];

  // ===== emb: ent = silu(obs @ Wemb + b_emb) ; phases 0..3 =====
  #pragma unroll
  for (int p = 0; p < 4; ++p) {
    PH_ISSUE(p + 1); WAITV2; BAR();
    if (p == 0) {
      #pragma unroll
      for (int ct = 0; ct < 4; ++ct) {
        f32x4 b_ = *(const f32x4*)(b_emb + ng * 64 + ct * 16 + g * 4);
        acc[0][ct] = b_; acc[1][ct] = b_;
      }
    }
    const char* ck = bst + (p & 1) * 16384;
    bf16x8 wf[4], xf[2];
    #pragma unroll
    for (int t = 0; t < 4; ++t) wf[t] = ld_frag(ck + ((ng * 4 + t) * 64 + lane) * 16);
    #pragma unroll
    for (int rt = 0; rt < 2; ++rt)
      xf[rt] = ld_frag(xb + ((mg * 2 + rt) * 16 + c) * 272 + p * 64 + g * 16);
    #pragma unroll
    for (int rt = 0; rt < 2; ++rt)
      #pragma unroll
      for (int ct = 0; ct < 4; ++ct) acc[rt][ct] = MFMA16(wf[ct], xf[rt], acc[rt][ct]);
    WAITLG; BAR();
  }

  // ---- silu + LN1 ----
  #pragma unroll
  for (int rt = 0; rt < 2; ++rt)
    #pragma unroll
    for (int ct = 0; ct < 4; ++ct)
      #pragma unroll
      for (int r = 0; r < 4; ++r) acc[rt][ct][r] = silu_f(acc[rt][ct][r]);
  #pragma unroll
  for (int rt = 0; rt < 2; ++rt) {
    float s1 = 0.f, s2 = 0.f;
    #pragma unroll
    for (int ct = 0; ct < 4; ++ct)
      #pragma unroll
      for (int r = 0; r < 4; ++r) { float e = acc[rt][ct][r]; s1 += e; s2 += e * e; }
    s1 += __shfl_xor(s1, 16); s2 += __shfl_xor(s2, 16);
    s1 += __shfl_xor(s1, 32); s2 += __shfl_xor(s2, 32);
    if (g == 0)
      *(float2*)(lds + L_PP + (mg * 32 + rt * 16 + c) * 48 + ng * 8) = make_float2(s1, s2);
  }
  WAITLG; BAR();
  uint2 respk[2][4];
  {
    float mu[2], rs[2];
    #pragma unroll
    for (int rt = 0; rt < 2; ++rt) {
      int row = mg * 32 + rt * 16 + c;
      f32x4 pA = *(const f32x4*)(lds + L_PP + row * 48);
      f32x4 pB = *(const f32x4*)(lds + L_PP + row * 48 + 16);
      float S1 = pA[0] + pA[2] + pB[0] + pB[2];
      float S2 = pA[1] + pA[3] + pB[1] + pB[3];
      float m_ = S1 * (1.f / 256.f);
      float v_ = S2 * (1.f / 256.f) - m_ * m_;
      mu[rt] = m_; rs[rt] = rsqrtf(v_ + 1e-5f);
    }
    #pragma unroll
    for (int rt = 0; rt < 2; ++rt)
      #pragma unroll
      for (int ct = 0; ct < 4; ++ct) {
        f32x4 xv;
        #pragma unroll
        for (int r = 0; r < 4; ++r) xv[r] = (acc[rt][ct][r] - mu[rt]) * rs[rt];
        uint2 xp = pack4(xv);
        respk[rt][ct] = xp;
        *(uint2*)(xb + xaddr(mg * 32 + rt * 16 + c, ng * 64 + ct * 16 + g * 4)) = xp;
      }
  }
  WAITLG; BAR();

  // ===== Q (4..11), K (12..19) weights-as-A ; V (20..27) x-as-A =====
  uint2 q_pk[2][4], k_pk[2][4], v_pk[2][4];
  #pragma unroll
  for (int p = 4; p < 28; ++p) {
    if (p < 27) { PH_ISSUE(p + 1); WAITV2; } else { WAITV0; }
    BAR();
    if (p == 4) {
      #pragma unroll
      for (int ct = 0; ct < 4; ++ct) {
        f32x4 b_ = *(const f32x4*)(bq + ng * 64 + ct * 16 + g * 4);
        acc[0][ct] = b_; acc[1][ct] = b_;
      }
    }
    if (p == 12) {
      #pragma unroll
      for (int rt = 0; rt < 2; ++rt)
        #pragma unroll
        for (int ct = 0; ct < 4; ++ct) q_pk[rt][ct] = pack4(acc[rt][ct]);
      #pragma unroll
      for (int ct = 0; ct < 4; ++ct) {
        f32x4 b_ = *(const f32x4*)(bk + ng * 64 + ct * 16 + g * 4);
        acc[0][ct] = b_; acc[1][ct] = b_;
      }
    }
    if (p == 20) {
      #pragma unroll
      for (int rt = 0; rt < 2; ++rt)
        #pragma unroll
        for (int ct = 0; ct < 4; ++ct) k_pk[rt][ct] = pack4(acc[rt][ct]);
      #pragma unroll
      for (int ct = 0; ct < 4; ++ct) {
        f32x4 b_ = splat4(bv[ng * 64 + ct * 16 + c]);   // x-as-A: n = col = c
        acc[0][ct] = b_; acc[1][ct] = b_;
      }
    }
    const char* ck = bst + (p & 1) * 16384;
    const int ks = (p - 4) & 7;
    bf16x8 wf[4], xf[2];
    #pragma unroll
    for (int t = 0; t < 4; ++t) wf[t] = ld_frag(ck + ((ng * 4 + t) * 64 + lane) * 16);
    #pragma unroll
    for (int rt = 0; rt < 2; ++rt)
      xf[rt] = ld_frag(xb + (((mg * 2 + rt) * 8 + ks) * 64 + lane) * 16);
    if (p < 20) {
      #pragma unroll
      for (int rt = 0; rt < 2; ++rt)
        #pragma unroll
        for (int ct = 0; ct < 4; ++ct) acc[rt][ct] = MFMA16(wf[ct], xf[rt], acc[rt][ct]);
    } else {
      #pragma unroll
      for (int rt = 0; rt < 2; ++rt)
        #pragma unroll
        for (int ct = 0; ct < 4; ++ct) acc[rt][ct] = MFMA16(xf[rt], wf[ct], acc[rt][ct]);
    }
    WAITLG; BAR();
  }
  #pragma unroll
  for (int rt = 0; rt < 2; ++rt)
    #pragma unroll
    for (int ct = 0; ct < 4; ++ct) v_pk[rt][ct] = pack4(acc[rt][ct]);

  // ===== attention (wave-local: batch mg, head ng); scratch overlays staging =====
  {
    f32x4 sacc[2][2];
    sacc[0][0] = splat4(0.f); sacc[0][1] = splat4(0.f);
    sacc[1][0] = splat4(0.f); sacc[1][1] = splat4(0.f);
    #pragma unroll
    for (int hf = 0; hf < 2; ++hf) {
      #pragma unroll
      for (int rt2 = 0; rt2 < 2; ++rt2)
        #pragma unroll
        for (int ctl = 0; ctl < 2; ++ctl) {
          *(uint2*)(as_ + (rt2 * 16 + c) * 64 + (ctl * 16 + g * 4) * 2) = q_pk[rt2][hf * 2 + ctl];
          *(uint2*)(as_ + 2048 + (rt2 * 16 + c) * 64 + (ctl * 16 + g * 4) * 2) = k_pk[rt2][hf * 2 + ctl];
        }
      WAITLG;
      bf16x8 qf[2], kf[2];
      #pragma unroll
      for (int t = 0; t < 2; ++t) {
        qf[t] = ld_frag(as_ + (t * 16 + c) * 64 + g * 16);
        kf[t] = ld_frag(as_ + 2048 + (t * 16 + c) * 64 + g * 16);
      }
      #pragma unroll
      for (int qt = 0; qt < 2; ++qt)
        #pragma unroll
        for (int kt = 0; kt < 2; ++kt)
          sacc[qt][kt] = MFMA16(kf[kt], qf[qt], sacc[qt][kt]);   // S^T
    }
    float rinv[2];
    uint2 p_pk[2][2];
    #pragma unroll
    for (int qt = 0; qt < 2; ++qt) {
      float sc[2][4];
      float mx = -3e38f;
      #pragma unroll
      for (int kt = 0; kt < 2; ++kt)
        #pragma unroll
        for (int r = 0; r < 4; ++r) { sc[kt][r] = sacc[qt][kt][r] * 0.125f; mx = fmaxf(mx, sc[kt][r]); }
      mx = fmaxf(mx, __shfl_xor(mx, 16));
      mx = fmaxf(mx, __shfl_xor(mx, 32));
      float sm = 0.f;
      #pragma unroll
      for (int kt = 0; kt < 2; ++kt)
        #pragma unroll
        for (int r = 0; r < 4; ++r) { float e = __expf(sc[kt][r] - mx); sc[kt][r] = e; sm += e; }
      sm += __shfl_xor(sm, 16);
      sm += __shfl_xor(sm, 32);
      rinv[qt] = 1.0f / sm;
      #pragma unroll
      for (int kt = 0; kt < 2; ++kt) {
        f32x4 pv = {sc[kt][0], sc[kt][1], sc[kt][2], sc[kt][3]};
        p_pk[qt][kt] = pack4(pv);
      }
    }
    // vT [64 d][64B = 32 agents] overlays q/k scratch
    #pragma unroll
    for (int rt2 = 0; rt2 < 2; ++rt2)
      #pragma unroll
      for (int ct = 0; ct < 4; ++ct)
        *(uint2*)(as_ + (ct * 16 + c) * 64 + (rt2 * 16 + g * 4) * 2) = v_pk[rt2][ct];
    WAITLG;
    bf16x8 vf[4];
    #pragma unroll
    for (int dt = 0; dt < 4; ++dt) vf[dt] = ld_frag(as_ + (dt * 16 + c) * 64 + g * 16);
    const int l1 = (g & 1) * 32 + c, l2 = l1 + 16;
    const bool hi = (g >= 2);
    #pragma unroll
    for (int qt = 0; qt < 2; ++qt) {
      unsigned x0k0 = __shfl(p_pk[qt][0].x, l1), x0k1 = __shfl(p_pk[qt][1].x, l1);
      unsigned y0k0 = __shfl(p_pk[qt][0].y, l1), y0k1 = __shfl(p_pk[qt][1].y, l1);
      unsigned x1k0 = __shfl(p_pk[qt][0].x, l2), x1k1 = __shfl(p_pk[qt][1].x, l2);
      unsigned y1k0 = __shfl(p_pk[qt][0].y, l2), y1k1 = __shfl(p_pk[qt][1].y, l2);
      bf16x8 pf = u4b(hi ? x0k1 : x0k0, hi ? y0k1 : y0k0, hi ? x1k1 : x1k0, hi ? y1k1 : y1k0);
      #pragma unroll
      for (int dt = 0; dt < 4; ++dt) {
        f32x4 o = splat4(0.f);
        o = MFMA16(vf[dt], pf, o);
        #pragma unroll
        for (int r = 0; r < 4; ++r) o[r] *= rinv[qt];
        *(uint2*)(xb + xaddr(mg * 32 + qt * 16 + c, ng * 64 + dt * 16 + g * 4)) = pack4(o);
      }
    }
  }
  WAITLG; BAR();

  // ===== O-GEMM: y = att @ Wo + bo + x ; phases 28..35 =====
  #pragma unroll
  for (int p = 28; p < 36; ++p) {
    if (p == 28) { PH_ISSUE(28); PH_ISSUE(29); WAITV2; }
    else if (p < 35) { PH_ISSUE(p + 1); WAITV2; }
    else { WAITV0; }
    BAR();
    if (p == 28) {
      #pragma unroll
      for (int ct = 0; ct < 4; ++ct) {
        f32x4 b_ = *(const f32x4*)(bo + ng * 64 + ct * 16 + g * 4);
        #pragma unroll
        for (int rt = 0; rt < 2; ++rt) acc[rt][ct] = b_ + unpk(respk[rt][ct]);
      }
    }
    const char* ck = bst + (p & 1) * 16384;
    const int ks = p - 28;
    bf16x8 wf[4], xf[2];
    #pragma unroll
    for (int t = 0; t < 4; ++t) wf[t] = ld_frag(ck + ((ng * 4 + t) * 64 + lane) * 16);
    #pragma unroll
    for (int rt = 0; rt < 2; ++rt)
      xf[rt] = ld_frag(xb + (((mg * 2 + rt) * 8 + ks) * 64 + lane) * 16);
    #pragma unroll
    for (int rt = 0; rt < 2; ++rt)
      #pragma unroll
      for (int ct = 0; ct < 4; ++ct) acc[rt][ct] = MFMA16(wf[ct], xf[rt], acc[rt][ct]);
    WAITLG; BAR();
  }

  // ---- LN2 + pool ----
  #pragma unroll
  for (int rt = 0; rt < 2; ++rt) {
    float s1 = 0.f, s2 = 0.f;
    #pragma unroll
    for (int ct = 0; ct < 4; ++ct)
      #pragma unroll
      for (int r = 0; r < 4; ++r) { float e = acc[rt][ct][r]; s1 += e; s2 += e * e; }
    s1 += __shfl_xor(s1, 16); s2 += __shfl_xor(s2, 16);
    s1 += __shfl_xor(s1, 32); s2 += __shfl_xor(s2, 32);
    if (g == 0)
      *(float2*)(lds + L_PP + (mg * 32 + rt * 16 + c) * 48 + ng * 8) = make_float2(s1, s2);
  }
  WAITLG; BAR();
  {
    float mu[2], rs[2];
    #pragma unroll
    for (int rt = 0; rt < 2; ++rt) {
      int row = mg * 32 + rt * 16 + c;
      f32x4 pA = *(const f32x4*)(lds + L_PP + row * 48);
      f32x4 pB = *(const f32x4*)(lds + L_PP + row * 48 + 16);
      float S1 = pA[0] + pA[2] + pB[0] + pB[2];
      float S2 = pA[1] + pA[3] + pB[1] + pB[3];
      float m_ = S1 * (1.f / 256.f);
      float v_ = S2 * (1.f / 256.f) - m_ * m_;
      mu[rt] = m_; rs[rt] = rsqrtf(v_ + 1e-5f);
    }
    f32x4 ps[4];
    #pragma unroll
    for (int ct = 0; ct < 4; ++ct) {
      #pragma unroll
      for (int r = 0; r < 4; ++r)
        ps[ct][r] = (acc[0][ct][r] - mu[0]) * rs[0] + (acc[1][ct][r] - mu[1]) * rs[1];
    }
    #pragma unroll
    for (int st = 1; st < 16; st <<= 1)
      #pragma unroll
      for (int ct = 0; ct < 4; ++ct)
        #pragma unroll
        for (int r = 0; r < 4; ++r) ps[ct][r] += __shfl_xor(ps[ct][r], st);
    if (c == 0) {
      #pragma unroll
      for (int ct = 0; ct < 4; ++ct) {
        f32x4 pv;
        #pragma unroll
        for (int r = 0; r < 4; ++r) pv[r] = ps[ct][r] * (1.f / 32.f);
        *(uint2*)(poolb + mg * 528 + (ng * 64 + ct * 16 + g * 4) * 2) = pack4(pv);
      }
    }
  }
  // zero pool/y1 rows 2..15 (cols 0..255)
  #pragma unroll
  for (int it = 0; it < 4; ++it) {
    int idx = it * 512 + tid;
    if (idx < 1792) {
      int row = 2 + (idx >> 7), col = idx & 127;
      *(unsigned*)(poolb + row * 528 + col * 4) = 0;
      *(unsigned*)(y1b + row * 528 + col * 4) = 0;
    }
  }
  WAITLG; BAR();

  // ===== tail MLP: M=16 MFMA (2 valid rows); wave wv owns cols wv*32..+31 =====
  f32x4 t1[2];
  #pragma unroll
  for (int ctl = 0; ctl < 2; ++ctl) t1[ctl] = splat4(b1[wv * 32 + ctl * 16 + c]);
  #pragma unroll
  for (int ks = 0; ks < 8; ++ks) {
    bf16x8 a = ld_frag(poolb + c * 528 + ks * 64 + g * 16);
    #pragma unroll
    for (int ctl = 0; ctl < 2; ++ctl) {
      bf16x8 b = *(const bf16x8*)(pw + OW1_ + (size_t)(((wv * 2 + ctl) * 8 + ks) * 64 + lane) * 8);
      t1[ctl] = MFMA16(a, b, t1[ctl]);
    }
  }
  if (g == 0) {
    #pragma unroll
    for (int ctl = 0; ctl < 2; ++ctl)
      #pragma unroll
      for (int r = 0; r < 4; ++r)
        *(__bf16*)(y1b + r * 528 + (wv * 32 + ctl * 16 + c) * 2) = (__bf16)silu_f(t1[ctl][r]);
  }
  WAITLG; BAR();
  f32x4 t2[2];
  #pragma unroll
  for (int ctl = 0; ctl < 2; ++ctl) t2[ctl] = splat4(b2[wv * 32 + ctl * 16 + c]);
  #pragma unroll
  for (int ks = 0; ks < 8; ++ks) {
    bf16x8 a = ld_frag(y1b + c * 528 + ks * 64 + g * 16);
    #pragma unroll
    for (int ctl = 0; ctl < 2; ++ctl) {
      bf16x8 b = *(const bf16x8*)(pw + OW2_ + (size_t)(((wv * 2 + ctl) * 8 + ks) * 64 + lane) * 8);
      t2[ctl] = MFMA16(a, b, t2[ctl]);
    }
  }
  if (g == 0) {
    float part[4] = {0.f, 0.f, 0.f, 0.f};
    #pragma unroll
    for (int ctl = 0; ctl < 2; ++ctl) {
      float wvv = Wval[wv * 32 + ctl * 16 + c];
      #pragma unroll
      for (int r = 0; r < 4; ++r) part[r] += silu_f(t2[ctl][r]) * wvv;
    }
    #pragma unroll
    for (int m = 1; m < 16; m <<= 1) {
      #pragma unroll
      for (int r = 0; r < 4; ++r) part[r] += __shfl_xor(part[r], m);
    }
    if (c == 0) {
      float4 p4 = make_float4(part[0], part[1], part[2], part[3]);
      *(float4*)(ptlb + wv * 16) = p4;
    }
  }
  WAITLG; BAR();
  if (tid < 2) {
    float s = Wval[256] + bval[0];
    const float* pt = (const float*)ptlb;
    #pragma unroll
    for (int w8 = 0; w8 < 8; ++w8) s += pt[w8 * 4 + tid];
    out[(size_t)blockIdx.x * 2 + tid] = s;
  }
}

extern "C" void kernel_launch(void* const* d_in, const int* in_sizes, int n_in,
                              void* d_out, int out_size, void* d_ws, size_t ws_size,
                              hipStream_t stream) {
  (void)in_sizes; (void)n_in; (void)out_size; (void)ws_size;
  const float* obs  = (const float*)d_in[0];
  const float* Wemb = (const float*)d_in[1];
  const float* bemb = (const float*)d_in[2];
  const float* Wq   = (const float*)d_in[3];
  const float* bq   = (const float*)d_in[4];
  const float* Wk   = (const float*)d_in[5];
  const float* bk   = (const float*)d_in[6];
  const float* Wv   = (const float*)d_in[7];
  const float* bv   = (const float*)d_in[8];
  const float* Wo   = (const float*)d_in[9];
  const float* bo   = (const float*)d_in[10];
  const float* W1   = (const float*)d_in[11];
  const float* b1   = (const float*)d_in[12];
  const float* W2   = (const float*)d_in[13];
  const float* b2   = (const float*)d_in[14];
  const float* Wval = (const float*)d_in[15];
  const float* bval = (const float*)d_in[16];
  ushort_t* ws = (ushort_t*)d_ws;
  float* out = (float*)d_out;

  pack_weights<<<208, 256, 0, stream>>>(Wemb, Wq, Wk, Wv, Wo, W1, W2, ws);
  poca_fused<<<4096, 512, 0, stream>>>(obs, ws, bemb, bq, bk, bv, bo, b1, b2, Wval, bval, out);
}